// Round 3
// baseline (386.738 us; speedup 1.0000x reference)
//
#include <hip/hip_runtime.h>
#include <cmath>

// SimplifiedSSM: B=2, L=2048, d_model=768, d_state=16, d_inner=1536
// ROUND 17: GEMM restructured to 2-wave blocks (128 thr), block tile 128x64,
// wave tile 64x64 (acc[4][4] -> 16 MFMA/wave/K-step, double R16), 2-buffer
// async staging (R14 barrier pattern). LDS 24KB -> up to 6 blocks/CU.
// R16 post-mortem: depth-3 vmcnt pipeline was neutral -> not latency-bound on
// HBM; wall/iter is sync-structural, so raise work-per-iter per wave instead.
#define DMODEL 768
#define DINNER 1536
#define NSTATE 16
#define SEQL   2048
#define NCHUNK 32
#define CHLEN  64      // SEQL / NCHUNK

#define DT_F32  0
#define DT_BF16 1
#define DT_ZERO 2

typedef __bf16 bf16x8 __attribute__((ext_vector_type(8)));
typedef float  f32x4  __attribute__((ext_vector_type(4)));

typedef __attribute__((address_space(3))) unsigned short lds_us;
typedef const __attribute__((address_space(1))) unsigned short glob_us;

__device__ __forceinline__ void async_cp16(glob_us* g, lds_us* l) {
    __builtin_amdgcn_global_load_lds((const __attribute__((address_space(1))) void*)g,
                                     (__attribute__((address_space(3))) void*)l, 16, 0, 0);
}

__device__ __forceinline__ float bf2f(unsigned short h) {
    union { unsigned u; float f; } v; v.u = ((unsigned)h) << 16; return v.f;
}
__device__ __forceinline__ unsigned short f2bf(float f) {
    union { float f; unsigned u; } v; v.f = f;
    unsigned r = (v.u + 0x7FFFu + ((v.u >> 16) & 1u)) >> 16;
    return (unsigned short)r;
}
__device__ int detect_dtype(const void* p) {
    const unsigned* u = (const unsigned*)p;
    int nzlo = 0, band = 0, anynz = 0;
    for (int i = 0; i < 64; ++i) {
        unsigned w = u[i];
        anynz |= (w != 0);
        unsigned lo = w & 0xFFFFu;
        if (lo) {
            ++nzlo;
            unsigned e8 = (lo >> 7) & 0xFF;
            if (e8 >= 0x60 && e8 <= 0x8E) ++band;
        }
    }
    if (nzlo >= 8) return (band * 2 > nzlo) ? DT_BF16 : DT_F32;
    return anynz ? DT_F32 : DT_ZERO;
}
__device__ __forceinline__ float LD(const void* p, size_t i, int dt) {
    if (dt == DT_BF16) return bf2f(((const unsigned short*)p)[i]);
    if (dt == DT_F32)  return ((const float*)p)[i];
    return 0.f;
}

// ---- fused prep: params->f32 | x->bf16 | 3 weight transposes ----
// blocks: [0,324) params, [324,3396) x, [3396,5700) in_w,
//         [5700,8004) dt_w, [8004,9156) out_w
__global__ __launch_bounds__(256) void prep_kernel(
    const void* __restrict__ x, const void* __restrict__ in_w,
    const void* __restrict__ cw, const void* __restrict__ cb,
    const void* __restrict__ xp, const void* __restrict__ dt_w,
    const void* __restrict__ db, const void* __restrict__ Al,
    const void* __restrict__ Dv, const void* __restrict__ out_w,
    unsigned short* __restrict__ xb, unsigned short* __restrict__ inT,
    unsigned short* __restrict__ dtT, unsigned short* __restrict__ outT,
    float* __restrict__ pf)
{
    __shared__ unsigned short tile[32][33];
    __shared__ int dts[6];
    const int blk = blockIdx.x;
    const int t   = threadIdx.x;

    if (blk < 324) {
        if (t == 0) {
            dts[0] = detect_dtype(cw); dts[1] = detect_dtype(cb);
            dts[2] = detect_dtype(db); dts[3] = detect_dtype(Al);
            dts[4] = detect_dtype(Dv); dts[5] = detect_dtype(xp);
        }
        __syncthreads();
        int g = blk * 256 + t;
        if (g >= 82944) return;
        const void* src; int local; int which;
        if      (g <  4608) { src = cw; local = g;         which = 0; }
        else if (g <  6144) { src = cb; local = g - 4608;  which = 1; }
        else if (g <  7680) { src = db; local = g - 6144;  which = 2; }
        else if (g < 32256) { src = Al; local = g - 7680;  which = 3; }
        else if (g < 33792) { src = Dv; local = g - 32256; which = 4; }
        else                { src = xp; local = g - 33792; which = 5; }
        pf[g] = LD(src, local, dts[which]);
    } else if (blk < 3396) {
        if (t == 0) dts[0] = detect_dtype(x);
        __syncthreads();
        const int dt = dts[0];
        size_t i = ((size_t)(blk - 324) * 256 + t) * 4;
        ushort4 o;
        o.x = f2bf(LD(x, i + 0, dt)); o.y = f2bf(LD(x, i + 1, dt));
        o.z = f2bf(LD(x, i + 2, dt)); o.w = f2bf(LD(x, i + 3, dt));
        *(ushort4*)&xb[i] = o;
    } else {
        const void* src; unsigned short* dst; int R, C, tx_n, idx;
        if (blk < 5700)      { src = in_w;  dst = inT;  R = 768;  C = 3072; tx_n = 96; idx = blk - 3396; }
        else if (blk < 8004) { src = dt_w;  dst = dtT;  R = 1536; C = 1536; tx_n = 48; idx = blk - 5700; }
        else                 { src = out_w; dst = outT; R = 1536; C = 768;  tx_n = 24; idx = blk - 8004; }
        if (t == 0) dts[0] = detect_dtype(src);
        __syncthreads();
        const int dt = dts[0];
        const int tx = t & 31, ty = t >> 5;
        const int bx = (idx % tx_n) * 32, by = (idx / tx_n) * 32;
        #pragma unroll
        for (int i = 0; i < 4; ++i) {
            int r = by + ty + i * 8;
            tile[ty + i * 8][tx] = f2bf(LD(src, (size_t)r * C + bx + tx, dt));
        }
        __syncthreads();
        #pragma unroll
        for (int i = 0; i < 4; ++i) {
            int c = bx + ty + i * 8;
            dst[(size_t)c * R + by + tx] = tile[tx][ty + i * 8];
        }
    }
}

// ---- MFMA GEMM: C = A[M][K] @ Bt[N][K]^T, 128x64 tile, 2 waves, 64x64/wave ----
// LDS granule rotation: slot (row, g) holds k-granule (g - (row>>1)) & 3
// (source-permuted async loads, linear LDS dst; reads use g=(quad+(row>>1))&3).
// Per thread per K-step: 6 async_cp16 (4 A + 2 B). 2-buffer, __syncthreads.
// EPI 1: bf16 C0 = softplus(v + biasf[col])
// EPI 2: f32  C0 = v (final output)
// EPI 3: col < N/2 -> bf16 C0 = v ; else bf16 C1 = silu(v)
template<int EPI>
__global__ __launch_bounds__(128) void gemm_kernel(
    const unsigned short* __restrict__ A, const unsigned short* __restrict__ Bt,
    void* __restrict__ C0, void* __restrict__ C1, const float* __restrict__ biasf,
    int M, int N, int K)
{
    __shared__ __align__(16) unsigned short As[2][128 * 32];   // 16 KB
    __shared__ __align__(16) unsigned short Bs[2][64 * 32];    // 8 KB
    const int t    = threadIdx.x;
    const int m0   = blockIdx.x * 128;
    const int n0   = blockIdx.y * 64;
    const int w    = t >> 6;             // 2 waves
    const int lane = t & 63;
    const int wm   = w * 64;             // wave owns rows [wm, wm+64), all 64 cols
    const int lm   = lane & 15, quad = lane >> 4;
    const int srow = lane >> 2;          // staging: row within 16-row group
    const int sg   = lane & 3;           // staging: granule slot

    f32x4 acc[4][4] = {};

    auto stage = [&](int k0, int q) {
        #pragma unroll
        for (int c = 0; c < 4; ++c) {
            int row = w * 64 + c * 16 + srow;
            int kg  = (sg - (row >> 1)) & 3;
            async_cp16((glob_us*)&A[(size_t)(m0 + row) * K + k0 + kg * 8],
                       (lds_us*)&As[q][(w * 64 + c * 16) * 32]);
        }
        #pragma unroll
        for (int c = 0; c < 2; ++c) {
            int row = w * 32 + c * 16 + srow;
            int kg  = (sg - (row >> 1)) & 3;
            async_cp16((glob_us*)&Bt[(size_t)(n0 + row) * K + k0 + kg * 8],
                       (lds_us*)&Bs[q][(w * 32 + c * 16) * 32]);
        }
    };

    // prologue: stage k0=0 into buffer 0
    stage(0, 0);

    int p = 0;
    for (int k0 = 0; k0 < K; k0 += 32) {
        __syncthreads();                       // drains stage(k0) into buf p
        if (k0 + 32 < K) stage(k0 + 32, p ^ 1);  // overlaps with MFMA below
        bf16x8 af[4], bfr[4];
        #pragma unroll
        for (int i = 0; i < 4; ++i) {
            int row = wm + i * 16 + lm;
            int g   = (quad + (row >> 1)) & 3;
            af[i] = *(const bf16x8*)&As[p][row * 32 + g * 8];
        }
        #pragma unroll
        for (int j = 0; j < 4; ++j) {
            int row = j * 16 + lm;
            int g   = (quad + (row >> 1)) & 3;
            bfr[j] = *(const bf16x8*)&Bs[p][row * 32 + g * 8];
        }
        #pragma unroll
        for (int i = 0; i < 4; ++i)
            #pragma unroll
            for (int j = 0; j < 4; ++j)
                acc[i][j] = __builtin_amdgcn_mfma_f32_16x16x32_bf16(af[i], bfr[j], acc[i][j], 0, 0, 0);
        p ^= 1;
    }

    const int half = N >> 1;
    #pragma unroll
    for (int i = 0; i < 4; ++i) {
        #pragma unroll
        for (int j = 0; j < 4; ++j) {
            int col = n0 + j * 16 + lm;
            #pragma unroll
            for (int r = 0; r < 4; ++r) {
                int row = m0 + wm + i * 16 + quad * 4 + r;
                float v = acc[i][j][r];
                if (EPI == 1) {
                    v += biasf[col];
                    float sp = (v > 20.f) ? v : log1pf(__expf(v));
                    ((unsigned short*)C0)[(size_t)row * N + col] = f2bf(sp);
                } else if (EPI == 2) {
                    ((float*)C0)[(size_t)row * N + col] = v;
                } else {
                    if (col < half) {
                        ((unsigned short*)C0)[(size_t)row * half + col] = f2bf(v);
                    } else {
                        float s = v / (1.f + __expf(-v));
                        ((unsigned short*)C1)[(size_t)row * half + col - half] = f2bf(s);
                    }
                }
            }
        }
    }
}

// ---- depthwise conv3 + bias + SiLU ----
__global__ __launch_bounds__(256) void conv_silu_kernel(
    const unsigned short* __restrict__ xcpre, const float* __restrict__ cwf,
    const float* __restrict__ cbf, unsigned short* __restrict__ xcb)
{
    int idx = blockIdx.x * 256 + threadIdx.x;
    int d   = idx % DINNER;
    int row = idx / DINNER;
    int l   = row % SEQL;
    size_t base = (size_t)row * DINNER + d;
    float acc = cbf[d];
    if (l > 0)        acc += bf2f(xcpre[base - DINNER]) * cwf[d * 3 + 0];
    acc += bf2f(xcpre[base]) * cwf[d * 3 + 1];
    if (l < SEQL - 1) acc += bf2f(xcpre[base + DINNER]) * cwf[d * 3 + 2];
    float s = acc / (1.f + __expf(-acc));
    xcb[base] = f2bf(s);
}

// ---- x_proj: BC[row][32] = xc[row][:] @ xproj_f[1536][32] ----
__global__ __launch_bounds__(128) void xproj_kernel(
    const unsigned short* __restrict__ xcb, const float* __restrict__ wf,
    float* __restrict__ BC)
{
    __shared__ float red[4][32][4];
    const int t = threadIdx.x;
    const int s = t & 31, part = t >> 5;
    const int row0 = blockIdx.x * 4;
    float acc[4] = {0.f, 0.f, 0.f, 0.f};
    for (int k = part * 384; k < (part + 1) * 384; ++k) {
        float wv = wf[k * 32 + s];
        #pragma unroll
        for (int r = 0; r < 4; ++r)
            acc[r] += bf2f(xcb[(size_t)(row0 + r) * DINNER + k]) * wv;
    }
    #pragma unroll
    for (int r = 0; r < 4; ++r) red[part][s][r] = acc[r];
    __syncthreads();
    if (t < 32) {
        #pragma unroll
        for (int r = 0; r < 4; ++r)
            BC[(size_t)(row0 + r) * 32 + t] =
                red[0][t][r] + red[1][t][r] + red[2][t][r] + red[3][t][r];
    }
}

// ================= register-state chunked scan (spill-free) =================
__global__ __launch_bounds__(256) void scan_phase_a(
    const unsigned short* __restrict__ dlt, const unsigned short* __restrict__ xcb,
    const float* __restrict__ BC, const float* __restrict__ A_log_f,
    unsigned short* __restrict__ P, float* __restrict__ S)
{
    int g = blockIdx.x * 256 + threadIdx.x;
    int d = g % DINNER;
    int c = (g / DINNER) % NCHUNK;
    int b = g / (DINNER * NCHUNK);
    f32x4 A4[4], h4[4];
    const f32x4* al4 = (const f32x4*)&A_log_f[d * 16];
    #pragma unroll
    for (int q = 0; q < 4; ++q) {
        f32x4 al = al4[q];
        f32x4 a;
        a[0] = -__expf(al[0]); a[1] = -__expf(al[1]);
        a[2] = -__expf(al[2]); a[3] = -__expf(al[3]);
        A4[q] = a;
        h4[q] = (f32x4){0.f, 0.f, 0.f, 0.f};
    }
    float sdv = 0.f;
    const int row0 = b * SEQL + c * CHLEN;
    for (int l = 0; l < CHLEN; ++l) {
        size_t row = (size_t)(row0 + l);
        float dv = bf2f(dlt[row * DINNER + d]);
        float xv = bf2f(xcb[row * DINNER + d]);
        float dx = dv * xv;
        sdv += dv;
        const f32x4* bc4 = (const f32x4*)&BC[row * 32];
        #pragma unroll
        for (int q = 0; q < 4; ++q) {
            f32x4 Bq = bc4[q];
            f32x4 e;
            e[0] = __expf(dv * A4[q][0]); e[1] = __expf(dv * A4[q][1]);
            e[2] = __expf(dv * A4[q][2]); e[3] = __expf(dv * A4[q][3]);
            h4[q] = e * h4[q] + dx * Bq;
        }
    }
    size_t idx = (((size_t)(b * NCHUNK + c)) * DINNER + d) * 16;
    #pragma unroll
    for (int q = 0; q < 4; ++q) {
        *(f32x4*)&S[idx + q * 4] = h4[q];
        ushort4 pq;
        pq.x = f2bf(__expf(sdv * A4[q][0]));
        pq.y = f2bf(__expf(sdv * A4[q][1]));
        pq.z = f2bf(__expf(sdv * A4[q][2]));
        pq.w = f2bf(__expf(sdv * A4[q][3]));
        *(ushort4*)&P[idx + q * 4] = pq;
    }
}

__global__ __launch_bounds__(256) void scan_combine(
    const unsigned short* __restrict__ P, float* __restrict__ S)
{
    int t = blockIdx.x * 256 + threadIdx.x;            // < 2*1536*16
    int b = t / (DINNER * NSTATE);
    int dn = t % (DINNER * NSTATE);
    float H = 0.f;
    for (int c = 0; c < NCHUNK; ++c) {
        size_t idx = ((size_t)(b * NCHUNK + c)) * (DINNER * NSTATE) + dn;
        float Pv = bf2f(P[idx]);
        float Sv = S[idx];
        S[idx] = H;                 // Hin for chunk c
        H = Pv * H + Sv;
    }
}

__global__ __launch_bounds__(256) void scan_phase_c(
    const unsigned short* __restrict__ dlt, const unsigned short* __restrict__ xcb,
    const float* __restrict__ BC, const unsigned short* __restrict__ zg,
    const float* __restrict__ A_log_f, const float* __restrict__ D_f,
    const float* __restrict__ Hin, unsigned short* __restrict__ yg)
{
    int g = blockIdx.x * 256 + threadIdx.x;
    int d = g % DINNER;
    int c = (g / DINNER) % NCHUNK;
    int b = g / (DINNER * NCHUNK);
    f32x4 A4[4], h4[4];
    const f32x4* al4 = (const f32x4*)&A_log_f[d * 16];
    size_t hidx = (((size_t)(b * NCHUNK + c)) * DINNER + d) * 16;
    const f32x4* hin4 = (const f32x4*)&Hin[hidx];
    #pragma unroll
    for (int q = 0; q < 4; ++q) {
        f32x4 al = al4[q];
        f32x4 a;
        a[0] = -__expf(al[0]); a[1] = -__expf(al[1]);
        a[2] = -__expf(al[2]); a[3] = -__expf(al[3]);
        A4[q] = a;
        h4[q] = hin4[q];
    }
    const float Dd = D_f[d];
    const int row0 = b * SEQL + c * CHLEN;
    for (int l = 0; l < CHLEN; ++l) {
        size_t row = (size_t)(row0 + l);
        float dv = bf2f(dlt[row * DINNER + d]);
        float xv = bf2f(xcb[row * DINNER + d]);
        float zv = bf2f(zg[row * DINNER + d]);
        float dx = dv * xv;
        const f32x4* bc4 = (const f32x4*)&BC[row * 32];
        f32x4 yv = (f32x4){0.f, 0.f, 0.f, 0.f};
        #pragma unroll
        for (int q = 0; q < 4; ++q) {
            f32x4 Bq = bc4[q];
            f32x4 Cq = bc4[4 + q];
            f32x4 e;
            e[0] = __expf(dv * A4[q][0]); e[1] = __expf(dv * A4[q][1]);
            e[2] = __expf(dv * A4[q][2]); e[3] = __expf(dv * A4[q][3]);
            h4[q] = e * h4[q] + dx * Bq;
            yv = yv + h4[q] * Cq;
        }
        float y = yv[0] + yv[1] + yv[2] + yv[3];
        yg[row * DINNER + d] = f2bf((y + Dd * xv) * zv);
    }
}

__global__ void guard_kernel(float* out, int code)
{
    if (threadIdx.x == 0 && blockIdx.x == 0 && code) out[0] = (float)code;
}

extern "C" void kernel_launch(void* const* d_in, const int* in_sizes, int n_in,
                              void* d_out, int out_size, void* d_ws, size_t ws_size,
                              hipStream_t stream) {
    static const int EXPECTED[10] = {3145728, 2359296, 4608, 1536, 49152,
                                     2359296, 1536, 24576, 1536, 1179648};
    bool ok = (n_in == 10);
    if (ok) for (int i = 0; i < 10; ++i) ok = ok && (in_sizes[i] == EXPECTED[i]);
    int code = 0;
    if (!ok) code = 2000;
    else if (ws_size < 67895296ULL) code = 3000;
    if (code) { guard_kernel<<<1, 64, 0, stream>>>((float*)d_out, code); return; }

    const void* x       = d_in[0];
    const void* in_w    = d_in[1];
    const void* conv_w  = d_in[2];
    const void* conv_b  = d_in[3];
    const void* xproj_w = d_in[4];
    const void* dt_w    = d_in[5];
    const void* dt_b    = d_in[6];
    const void* A_log   = d_in[7];
    const void* Dvec    = d_in[8];
    const void* out_w   = d_in[9];

    char* ws = (char*)d_ws;
    float* conv_w_f = (float*)(ws + 0);        // 4608
    float* conv_b_f = (float*)(ws + 18432);    // 1536
    float* dt_b_f   = (float*)(ws + 24576);    // 1536
    float* A_log_f  = (float*)(ws + 30720);    // 24576
    float* D_f      = (float*)(ws + 129024);   // 1536
    float* xproj_f  = (float*)(ws + 135168);   // 49152
    unsigned short* xb    = (unsigned short*)(ws + 524288);    // [4096][768]  (dead after gemm1)
    unsigned short* inT   = (unsigned short*)(ws + 6815744);   // [3072][768]  (dead after gemm1)
    unsigned short* yg    = (unsigned short*)(ws + 524288);    // [4096][1536] alias xb+inT
    unsigned short* dtT   = (unsigned short*)(ws + 13107200);  // [1536][1536]
    unsigned short* outT  = (unsigned short*)(ws + 17825792);  // [768][1536]
    unsigned short* xcpre = (unsigned short*)(ws + 20185088);  // [4096][1536] (dead after conv)
    unsigned short* dlt   = xcpre;                             // alias (gemm2 out)
    float*          BC    = (float*)(ws + 32768000);           // [4096][32]
    unsigned short* zg    = (unsigned short*)(ws + 33292288);  // [4096][1536] silu(z)
    unsigned short* xcb   = (unsigned short*)(ws + 45875200);  // [4096][1536]
    float*          scanS = (float*)(ws + 58458112);           // [2][32][1536][16] f32 6.29MB
    unsigned short* scanP = (unsigned short*)(ws + 64749568);  // same shape bf16   3.15MB

    prep_kernel<<<9156, 256, 0, stream>>>(x, in_w, conv_w, conv_b, xproj_w, dt_w,
                                          dt_b, A_log, Dvec, out_w,
                                          xb, inT, dtT, outT, (float*)ws);

    gemm_kernel<3><<<dim3(32, 48), 128, 0, stream>>>(xb, inT, (void*)xcpre, (void*)zg,
                                                     nullptr, 4096, 3072, 768);
    conv_silu_kernel<<<(4096 * DINNER) / 256, 256, 0, stream>>>(xcpre, conv_w_f, conv_b_f, xcb);
    xproj_kernel<<<1024, 128, 0, stream>>>(xcb, xproj_f, BC);
    gemm_kernel<1><<<dim3(32, 24), 128, 0, stream>>>(xcb, dtT, (void*)dlt, nullptr,
                                                     dt_b_f, 4096, 1536, 1536);
    scan_phase_a<<<384, 256, 0, stream>>>(dlt, xcb, BC, A_log_f, scanP, scanS);
    scan_combine<<<192, 256, 0, stream>>>(scanP, scanS);
    scan_phase_c<<<384, 256, 0, stream>>>(dlt, xcb, BC, zg, A_log_f, D_f, scanS, yg);
    gemm_kernel<2><<<dim3(32, 12), 128, 0, stream>>>(yg, outT, d_out, nullptr,
                                                    nullptr, 4096, 768, 1536);
}

// Round 4
// 357.450 us; speedup vs baseline: 1.0819x; 1.0819x over previous
//
#include <hip/hip_runtime.h>
#include <cmath>

// SimplifiedSSM: B=2, L=2048, d_model=768, d_state=16, d_inner=1536
// ROUND 18: GEMM reverted to R14 (proven best: 4 waves, 128x64, 2-buffer,
// granule rotation -- R15/16/17 all regressed). NEW: scan q-split -- d_state
// split across 4 lanes (q=lane&3 owns one f32x4 of 16 states): 4x wave
// parallelism (6 -> 24 waves/CU) for the latency-bound scan phases; phase_c
// C-dot reduced via 2x shfl_xor; S/P layout unchanged (combine untouched).
#define DMODEL 768
#define DINNER 1536
#define NSTATE 16
#define SEQL   2048
#define NCHUNK 32
#define CHLEN  64      // SEQL / NCHUNK

#define DT_F32  0
#define DT_BF16 1
#define DT_ZERO 2

typedef __bf16 bf16x8 __attribute__((ext_vector_type(8)));
typedef float  f32x4  __attribute__((ext_vector_type(4)));

typedef __attribute__((address_space(3))) unsigned short lds_us;
typedef const __attribute__((address_space(1))) unsigned short glob_us;

__device__ __forceinline__ void async_cp16(glob_us* g, lds_us* l) {
    __builtin_amdgcn_global_load_lds((const __attribute__((address_space(1))) void*)g,
                                     (__attribute__((address_space(3))) void*)l, 16, 0, 0);
}

__device__ __forceinline__ float bf2f(unsigned short h) {
    union { unsigned u; float f; } v; v.u = ((unsigned)h) << 16; return v.f;
}
__device__ __forceinline__ unsigned short f2bf(float f) {
    union { float f; unsigned u; } v; v.f = f;
    unsigned r = (v.u + 0x7FFFu + ((v.u >> 16) & 1u)) >> 16;
    return (unsigned short)r;
}
__device__ int detect_dtype(const void* p) {
    const unsigned* u = (const unsigned*)p;
    int nzlo = 0, band = 0, anynz = 0;
    for (int i = 0; i < 64; ++i) {
        unsigned w = u[i];
        anynz |= (w != 0);
        unsigned lo = w & 0xFFFFu;
        if (lo) {
            ++nzlo;
            unsigned e8 = (lo >> 7) & 0xFF;
            if (e8 >= 0x60 && e8 <= 0x8E) ++band;
        }
    }
    if (nzlo >= 8) return (band * 2 > nzlo) ? DT_BF16 : DT_F32;
    return anynz ? DT_F32 : DT_ZERO;
}
__device__ __forceinline__ float LD(const void* p, size_t i, int dt) {
    if (dt == DT_BF16) return bf2f(((const unsigned short*)p)[i]);
    if (dt == DT_F32)  return ((const float*)p)[i];
    return 0.f;
}

// ---- fused prep: params->f32 | x->bf16 | 3 weight transposes ----
// blocks: [0,324) params, [324,3396) x, [3396,5700) in_w,
//         [5700,8004) dt_w, [8004,9156) out_w
__global__ __launch_bounds__(256) void prep_kernel(
    const void* __restrict__ x, const void* __restrict__ in_w,
    const void* __restrict__ cw, const void* __restrict__ cb,
    const void* __restrict__ xp, const void* __restrict__ dt_w,
    const void* __restrict__ db, const void* __restrict__ Al,
    const void* __restrict__ Dv, const void* __restrict__ out_w,
    unsigned short* __restrict__ xb, unsigned short* __restrict__ inT,
    unsigned short* __restrict__ dtT, unsigned short* __restrict__ outT,
    float* __restrict__ pf)
{
    __shared__ unsigned short tile[32][33];
    __shared__ int dts[6];
    const int blk = blockIdx.x;
    const int t   = threadIdx.x;

    if (blk < 324) {
        if (t == 0) {
            dts[0] = detect_dtype(cw); dts[1] = detect_dtype(cb);
            dts[2] = detect_dtype(db); dts[3] = detect_dtype(Al);
            dts[4] = detect_dtype(Dv); dts[5] = detect_dtype(xp);
        }
        __syncthreads();
        int g = blk * 256 + t;
        if (g >= 82944) return;
        const void* src; int local; int which;
        if      (g <  4608) { src = cw; local = g;         which = 0; }
        else if (g <  6144) { src = cb; local = g - 4608;  which = 1; }
        else if (g <  7680) { src = db; local = g - 6144;  which = 2; }
        else if (g < 32256) { src = Al; local = g - 7680;  which = 3; }
        else if (g < 33792) { src = Dv; local = g - 32256; which = 4; }
        else                { src = xp; local = g - 33792; which = 5; }
        pf[g] = LD(src, local, dts[which]);
    } else if (blk < 3396) {
        if (t == 0) dts[0] = detect_dtype(x);
        __syncthreads();
        const int dt = dts[0];
        size_t i = ((size_t)(blk - 324) * 256 + t) * 4;
        ushort4 o;
        o.x = f2bf(LD(x, i + 0, dt)); o.y = f2bf(LD(x, i + 1, dt));
        o.z = f2bf(LD(x, i + 2, dt)); o.w = f2bf(LD(x, i + 3, dt));
        *(ushort4*)&xb[i] = o;
    } else {
        const void* src; unsigned short* dst; int R, C, tx_n, idx;
        if (blk < 5700)      { src = in_w;  dst = inT;  R = 768;  C = 3072; tx_n = 96; idx = blk - 3396; }
        else if (blk < 8004) { src = dt_w;  dst = dtT;  R = 1536; C = 1536; tx_n = 48; idx = blk - 5700; }
        else                 { src = out_w; dst = outT; R = 1536; C = 768;  tx_n = 24; idx = blk - 8004; }
        if (t == 0) dts[0] = detect_dtype(src);
        __syncthreads();
        const int dt = dts[0];
        const int tx = t & 31, ty = t >> 5;
        const int bx = (idx % tx_n) * 32, by = (idx / tx_n) * 32;
        #pragma unroll
        for (int i = 0; i < 4; ++i) {
            int r = by + ty + i * 8;
            tile[ty + i * 8][tx] = f2bf(LD(src, (size_t)r * C + bx + tx, dt));
        }
        __syncthreads();
        #pragma unroll
        for (int i = 0; i < 4; ++i) {
            int c = bx + ty + i * 8;
            dst[(size_t)c * R + by + tx] = tile[tx][ty + i * 8];
        }
    }
}

// ---- MFMA GEMM: C = A[M][K] @ Bt[N][K]^T, 128x64 tile, double-buffered async ----
// (R14 structure, verbatim.) LDS granule rotation: slot (row, g) holds
// k-granule (g - (row>>1)) & 3.
// EPI 1: bf16 C0 = softplus(v + biasf[col])
// EPI 2: f32  C0 = v (final output)
// EPI 3: col < N/2 -> bf16 C0 = v ; else bf16 C1 = silu(v)
template<int EPI>
__global__ __launch_bounds__(256) void gemm_kernel(
    const unsigned short* __restrict__ A, const unsigned short* __restrict__ Bt,
    void* __restrict__ C0, void* __restrict__ C1, const float* __restrict__ biasf,
    int M, int N, int K)
{
    __shared__ __align__(16) unsigned short As[2][128 * 32];   // 16 KB
    __shared__ __align__(16) unsigned short Bs[2][64 * 32];    // 8 KB
    const int t    = threadIdx.x;
    const int m0   = blockIdx.x * 128;
    const int n0   = blockIdx.y * 64;
    const int w    = t >> 6;
    const int lane = t & 63;
    const int wm   = (w >> 1) * 64, wn = (w & 1) * 32;
    const int lm   = lane & 15, quad = lane >> 4;
    const int srow = lane >> 2;          // staging: row within 16-row group
    const int sg   = lane & 3;           // staging: granule slot

    f32x4 acc[4][2] = {};

    // prologue: stage k0=0 into buffer 0
    #pragma unroll
    for (int h = 0; h < 2; ++h) {
        int row = w * 32 + h * 16 + srow;
        int kg  = (sg - (row >> 1)) & 3;
        async_cp16((glob_us*)&A[(size_t)(m0 + row) * K + kg * 8],
                   (lds_us*)&As[0][(w * 32 + h * 16) * 32]);
    }
    {
        int brow = w * 16 + srow;
        int bkg  = (sg - (brow >> 1)) & 3;
        async_cp16((glob_us*)&Bt[(size_t)(n0 + brow) * K + bkg * 8],
                   (lds_us*)&Bs[0][(w * 16) * 32]);
    }

    int p = 0;
    for (int k0 = 0; k0 < K; k0 += 32) {
        __syncthreads();                       // drains stage(k0); reads of buf p^1 long done
        if (k0 + 32 < K) {                     // stage k0+32 into the other buffer (overlaps MFMA)
            #pragma unroll
            for (int h = 0; h < 2; ++h) {
                int row = w * 32 + h * 16 + srow;
                int kg  = (sg - (row >> 1)) & 3;
                async_cp16((glob_us*)&A[(size_t)(m0 + row) * K + k0 + 32 + kg * 8],
                           (lds_us*)&As[p ^ 1][(w * 32 + h * 16) * 32]);
            }
            int brow = w * 16 + srow;
            int bkg  = (sg - (brow >> 1)) & 3;
            async_cp16((glob_us*)&Bt[(size_t)(n0 + brow) * K + k0 + 32 + bkg * 8],
                       (lds_us*)&Bs[p ^ 1][(w * 16) * 32]);
        }
        bf16x8 af[4], bfr[2];
        #pragma unroll
        for (int i = 0; i < 4; ++i) {
            int row = wm + i * 16 + lm;
            int g   = (quad + (row >> 1)) & 3;
            af[i] = *(const bf16x8*)&As[p][row * 32 + g * 8];
        }
        #pragma unroll
        for (int j = 0; j < 2; ++j) {
            int row = wn + j * 16 + lm;
            int g   = (quad + (row >> 1)) & 3;
            bfr[j] = *(const bf16x8*)&Bs[p][row * 32 + g * 8];
        }
        #pragma unroll
        for (int i = 0; i < 4; ++i)
            #pragma unroll
            for (int j = 0; j < 2; ++j)
                acc[i][j] = __builtin_amdgcn_mfma_f32_16x16x32_bf16(af[i], bfr[j], acc[i][j], 0, 0, 0);
        p ^= 1;
    }

    const int half = N >> 1;
    #pragma unroll
    for (int i = 0; i < 4; ++i) {
        #pragma unroll
        for (int j = 0; j < 2; ++j) {
            int col = n0 + wn + j * 16 + lm;
            #pragma unroll
            for (int r = 0; r < 4; ++r) {
                int row = m0 + wm + i * 16 + quad * 4 + r;
                float v = acc[i][j][r];
                if (EPI == 1) {
                    v += biasf[col];
                    float sp = (v > 20.f) ? v : log1pf(__expf(v));
                    ((unsigned short*)C0)[(size_t)row * N + col] = f2bf(sp);
                } else if (EPI == 2) {
                    ((float*)C0)[(size_t)row * N + col] = v;
                } else {
                    if (col < half) {
                        ((unsigned short*)C0)[(size_t)row * half + col] = f2bf(v);
                    } else {
                        float s = v / (1.f + __expf(-v));
                        ((unsigned short*)C1)[(size_t)row * half + col - half] = f2bf(s);
                    }
                }
            }
        }
    }
}

// ---- depthwise conv3 + bias + SiLU ----
__global__ __launch_bounds__(256) void conv_silu_kernel(
    const unsigned short* __restrict__ xcpre, const float* __restrict__ cwf,
    const float* __restrict__ cbf, unsigned short* __restrict__ xcb)
{
    int idx = blockIdx.x * 256 + threadIdx.x;
    int d   = idx % DINNER;
    int row = idx / DINNER;
    int l   = row % SEQL;
    size_t base = (size_t)row * DINNER + d;
    float acc = cbf[d];
    if (l > 0)        acc += bf2f(xcpre[base - DINNER]) * cwf[d * 3 + 0];
    acc += bf2f(xcpre[base]) * cwf[d * 3 + 1];
    if (l < SEQL - 1) acc += bf2f(xcpre[base + DINNER]) * cwf[d * 3 + 2];
    float s = acc / (1.f + __expf(-acc));
    xcb[base] = f2bf(s);
}

// ---- x_proj: BC[row][32] = xc[row][:] @ xproj_f[1536][32] ----
__global__ __launch_bounds__(128) void xproj_kernel(
    const unsigned short* __restrict__ xcb, const float* __restrict__ wf,
    float* __restrict__ BC)
{
    __shared__ float red[4][32][4];
    const int t = threadIdx.x;
    const int s = t & 31, part = t >> 5;
    const int row0 = blockIdx.x * 4;
    float acc[4] = {0.f, 0.f, 0.f, 0.f};
    for (int k = part * 384; k < (part + 1) * 384; ++k) {
        float wv = wf[k * 32 + s];
        #pragma unroll
        for (int r = 0; r < 4; ++r)
            acc[r] += bf2f(xcb[(size_t)(row0 + r) * DINNER + k]) * wv;
    }
    #pragma unroll
    for (int r = 0; r < 4; ++r) red[part][s][r] = acc[r];
    __syncthreads();
    if (t < 32) {
        #pragma unroll
        for (int r = 0; r < 4; ++r)
            BC[(size_t)(row0 + r) * 32 + t] =
                red[0][t][r] + red[1][t][r] + red[2][t][r] + red[3][t][r];
    }
}

// ============ register-state chunked scan, q-split (4 lanes per d) ============
// Thread g: q = g&3 owns states [4q,4q+4) of d = (g>>2)%DINNER.
// 4x wave parallelism vs R14 (1536 blocks, 24 waves/CU). S/P layout unchanged.
__global__ __launch_bounds__(256) void scan_phase_a(
    const unsigned short* __restrict__ dlt, const unsigned short* __restrict__ xcb,
    const float* __restrict__ BC, const float* __restrict__ A_log_f,
    unsigned short* __restrict__ P, float* __restrict__ S)
{
    int g = blockIdx.x * 256 + threadIdx.x;      // [0, 2*32*1536*4)
    int q = g & 3;
    int d = (g >> 2) % DINNER;
    int c = ((g >> 2) / DINNER) % NCHUNK;
    int b = (g >> 2) / (DINNER * NCHUNK);
    f32x4 al = *(const f32x4*)&A_log_f[d * 16 + q * 4];
    f32x4 A1;
    A1[0] = -__expf(al[0]); A1[1] = -__expf(al[1]);
    A1[2] = -__expf(al[2]); A1[3] = -__expf(al[3]);
    f32x4 h = (f32x4){0.f, 0.f, 0.f, 0.f};
    float sdv = 0.f;
    const int row0 = b * SEQL + c * CHLEN;
    for (int l = 0; l < CHLEN; ++l) {
        size_t row = (size_t)(row0 + l);
        float dv = bf2f(dlt[row * DINNER + d]);
        float xv = bf2f(xcb[row * DINNER + d]);
        float dx = dv * xv;
        sdv += dv;
        f32x4 Bq = *(const f32x4*)&BC[row * 32 + q * 4];
        f32x4 e;
        e[0] = __expf(dv * A1[0]); e[1] = __expf(dv * A1[1]);
        e[2] = __expf(dv * A1[2]); e[3] = __expf(dv * A1[3]);
        h = e * h + dx * Bq;
    }
    size_t idx = (((size_t)(b * NCHUNK + c)) * DINNER + d) * 16 + q * 4;
    *(f32x4*)&S[idx] = h;
    ushort4 pq;
    pq.x = f2bf(__expf(sdv * A1[0]));
    pq.y = f2bf(__expf(sdv * A1[1]));
    pq.z = f2bf(__expf(sdv * A1[2]));
    pq.w = f2bf(__expf(sdv * A1[3]));
    *(ushort4*)&P[idx] = pq;
}

__global__ __launch_bounds__(256) void scan_combine(
    const unsigned short* __restrict__ P, float* __restrict__ S)
{
    int t = blockIdx.x * 256 + threadIdx.x;            // < 2*1536*16
    int b = t / (DINNER * NSTATE);
    int dn = t % (DINNER * NSTATE);
    float H = 0.f;
    for (int c = 0; c < NCHUNK; ++c) {
        size_t idx = ((size_t)(b * NCHUNK + c)) * (DINNER * NSTATE) + dn;
        float Pv = bf2f(P[idx]);
        float Sv = S[idx];
        S[idx] = H;                 // Hin for chunk c
        H = Pv * H + Sv;
    }
}

__global__ __launch_bounds__(256) void scan_phase_c(
    const unsigned short* __restrict__ dlt, const unsigned short* __restrict__ xcb,
    const float* __restrict__ BC, const unsigned short* __restrict__ zg,
    const float* __restrict__ A_log_f, const float* __restrict__ D_f,
    const float* __restrict__ Hin, unsigned short* __restrict__ yg)
{
    int g = blockIdx.x * 256 + threadIdx.x;      // [0, 2*32*1536*4)
    int q = g & 3;
    int d = (g >> 2) % DINNER;
    int c = ((g >> 2) / DINNER) % NCHUNK;
    int b = (g >> 2) / (DINNER * NCHUNK);
    f32x4 al = *(const f32x4*)&A_log_f[d * 16 + q * 4];
    f32x4 A1;
    A1[0] = -__expf(al[0]); A1[1] = -__expf(al[1]);
    A1[2] = -__expf(al[2]); A1[3] = -__expf(al[3]);
    size_t hidx = (((size_t)(b * NCHUNK + c)) * DINNER + d) * 16 + q * 4;
    f32x4 h = *(const f32x4*)&Hin[hidx];
    const float Dd = D_f[d];
    const int row0 = b * SEQL + c * CHLEN;
    for (int l = 0; l < CHLEN; ++l) {
        size_t row = (size_t)(row0 + l);
        float dv = bf2f(dlt[row * DINNER + d]);
        float xv = bf2f(xcb[row * DINNER + d]);
        float dx = dv * xv;
        f32x4 Bq = *(const f32x4*)&BC[row * 32 + q * 4];
        f32x4 Cq = *(const f32x4*)&BC[row * 32 + 16 + q * 4];
        f32x4 e;
        e[0] = __expf(dv * A1[0]); e[1] = __expf(dv * A1[1]);
        e[2] = __expf(dv * A1[2]); e[3] = __expf(dv * A1[3]);
        h = e * h + dx * Bq;
        f32x4 yv = h * Cq;
        float y = yv[0] + yv[1] + yv[2] + yv[3];
        y += __shfl_xor(y, 1);                 // sum over q partners (lanes 4k..4k+3)
        y += __shfl_xor(y, 2);
        if (q == 0) {
            float zv = bf2f(zg[row * DINNER + d]);
            yg[row * DINNER + d] = f2bf((y + Dd * xv) * zv);
        }
    }
}

__global__ void guard_kernel(float* out, int code)
{
    if (threadIdx.x == 0 && blockIdx.x == 0 && code) out[0] = (float)code;
}

extern "C" void kernel_launch(void* const* d_in, const int* in_sizes, int n_in,
                              void* d_out, int out_size, void* d_ws, size_t ws_size,
                              hipStream_t stream) {
    static const int EXPECTED[10] = {3145728, 2359296, 4608, 1536, 49152,
                                     2359296, 1536, 24576, 1536, 1179648};
    bool ok = (n_in == 10);
    if (ok) for (int i = 0; i < 10; ++i) ok = ok && (in_sizes[i] == EXPECTED[i]);
    int code = 0;
    if (!ok) code = 2000;
    else if (ws_size < 67895296ULL) code = 3000;
    if (code) { guard_kernel<<<1, 64, 0, stream>>>((float*)d_out, code); return; }

    const void* x       = d_in[0];
    const void* in_w    = d_in[1];
    const void* conv_w  = d_in[2];
    const void* conv_b  = d_in[3];
    const void* xproj_w = d_in[4];
    const void* dt_w    = d_in[5];
    const void* dt_b    = d_in[6];
    const void* A_log   = d_in[7];
    const void* Dvec    = d_in[8];
    const void* out_w   = d_in[9];

    char* ws = (char*)d_ws;
    float* conv_w_f = (float*)(ws + 0);        // 4608
    float* conv_b_f = (float*)(ws + 18432);    // 1536
    float* dt_b_f   = (float*)(ws + 24576);    // 1536
    float* A_log_f  = (float*)(ws + 30720);    // 24576
    float* D_f      = (float*)(ws + 129024);   // 1536
    float* xproj_f  = (float*)(ws + 135168);   // 49152
    unsigned short* xb    = (unsigned short*)(ws + 524288);    // [4096][768]  (dead after gemm1)
    unsigned short* inT   = (unsigned short*)(ws + 6815744);   // [3072][768]  (dead after gemm1)
    unsigned short* yg    = (unsigned short*)(ws + 524288);    // [4096][1536] alias xb+inT
    unsigned short* dtT   = (unsigned short*)(ws + 13107200);  // [1536][1536]
    unsigned short* outT  = (unsigned short*)(ws + 17825792);  // [768][1536]
    unsigned short* xcpre = (unsigned short*)(ws + 20185088);  // [4096][1536] (dead after conv)
    unsigned short* dlt   = xcpre;                             // alias (gemm2 out)
    float*          BC    = (float*)(ws + 32768000);           // [4096][32]
    unsigned short* zg    = (unsigned short*)(ws + 33292288);  // [4096][1536] silu(z)
    unsigned short* xcb   = (unsigned short*)(ws + 45875200);  // [4096][1536]
    float*          scanS = (float*)(ws + 58458112);           // [2][32][1536][16] f32 6.29MB
    unsigned short* scanP = (unsigned short*)(ws + 64749568);  // same shape bf16   3.15MB

    prep_kernel<<<9156, 256, 0, stream>>>(x, in_w, conv_w, conv_b, xproj_w, dt_w,
                                          dt_b, A_log, Dvec, out_w,
                                          xb, inT, dtT, outT, (float*)ws);

    gemm_kernel<3><<<dim3(32, 48), 256, 0, stream>>>(xb, inT, (void*)xcpre, (void*)zg,
                                                     nullptr, 4096, 3072, 768);
    conv_silu_kernel<<<(4096 * DINNER) / 256, 256, 0, stream>>>(xcpre, conv_w_f, conv_b_f, xcb);
    xproj_kernel<<<1024, 128, 0, stream>>>(xcb, xproj_f, BC);
    gemm_kernel<1><<<dim3(32, 24), 256, 0, stream>>>(xcb, dtT, (void*)dlt, nullptr,
                                                     dt_b_f, 4096, 1536, 1536);
    scan_phase_a<<<1536, 256, 0, stream>>>(dlt, xcb, BC, A_log_f, scanP, scanS);
    scan_combine<<<192, 256, 0, stream>>>(scanP, scanS);
    scan_phase_c<<<1536, 256, 0, stream>>>(dlt, xcb, BC, zg, A_log_f, D_f, scanS, yg);
    gemm_kernel<2><<<dim3(32, 12), 256, 0, stream>>>(yg, outT, d_out, nullptr,
                                                    nullptr, 4096, 768, 1536);
}

// Round 5
// 345.555 us; speedup vs baseline: 1.1192x; 1.0344x over previous
//
#include <hip/hip_runtime.h>
#include <cmath>

// SimplifiedSSM: B=2, L=2048, d_model=768, d_state=16, d_inner=1536
// ROUND 19: scan software-pipelined. R18 showed 4x occupancy left phase_c
// duration unchanged (~2000 cy wall per 64-step iter vs ~100 cy work) ->
// per-iteration load->use serialization is the wall. Fix: ping-pong two
// 4-step register groups (loads for group g+1 issued before computing g;
// compiler emits counted vmcnt), phase_a + phase_c; 1-deep prefetch in
// combine. GEMMs stay at R14 proven structure. q-split layout kept.
#define DMODEL 768
#define DINNER 1536
#define NSTATE 16
#define SEQL   2048
#define NCHUNK 32
#define CHLEN  64      // SEQL / NCHUNK

#define DT_F32  0
#define DT_BF16 1
#define DT_ZERO 2

typedef __bf16 bf16x8 __attribute__((ext_vector_type(8)));
typedef float  f32x4  __attribute__((ext_vector_type(4)));

typedef __attribute__((address_space(3))) unsigned short lds_us;
typedef const __attribute__((address_space(1))) unsigned short glob_us;

__device__ __forceinline__ void async_cp16(glob_us* g, lds_us* l) {
    __builtin_amdgcn_global_load_lds((const __attribute__((address_space(1))) void*)g,
                                     (__attribute__((address_space(3))) void*)l, 16, 0, 0);
}

__device__ __forceinline__ float bf2f(unsigned short h) {
    union { unsigned u; float f; } v; v.u = ((unsigned)h) << 16; return v.f;
}
__device__ __forceinline__ unsigned short f2bf(float f) {
    union { float f; unsigned u; } v; v.f = f;
    unsigned r = (v.u + 0x7FFFu + ((v.u >> 16) & 1u)) >> 16;
    return (unsigned short)r;
}
__device__ int detect_dtype(const void* p) {
    const unsigned* u = (const unsigned*)p;
    int nzlo = 0, band = 0, anynz = 0;
    for (int i = 0; i < 64; ++i) {
        unsigned w = u[i];
        anynz |= (w != 0);
        unsigned lo = w & 0xFFFFu;
        if (lo) {
            ++nzlo;
            unsigned e8 = (lo >> 7) & 0xFF;
            if (e8 >= 0x60 && e8 <= 0x8E) ++band;
        }
    }
    if (nzlo >= 8) return (band * 2 > nzlo) ? DT_BF16 : DT_F32;
    return anynz ? DT_F32 : DT_ZERO;
}
__device__ __forceinline__ float LD(const void* p, size_t i, int dt) {
    if (dt == DT_BF16) return bf2f(((const unsigned short*)p)[i]);
    if (dt == DT_F32)  return ((const float*)p)[i];
    return 0.f;
}

// ---- fused prep: params->f32 | x->bf16 | 3 weight transposes ----
// blocks: [0,324) params, [324,3396) x, [3396,5700) in_w,
//         [5700,8004) dt_w, [8004,9156) out_w
__global__ __launch_bounds__(256) void prep_kernel(
    const void* __restrict__ x, const void* __restrict__ in_w,
    const void* __restrict__ cw, const void* __restrict__ cb,
    const void* __restrict__ xp, const void* __restrict__ dt_w,
    const void* __restrict__ db, const void* __restrict__ Al,
    const void* __restrict__ Dv, const void* __restrict__ out_w,
    unsigned short* __restrict__ xb, unsigned short* __restrict__ inT,
    unsigned short* __restrict__ dtT, unsigned short* __restrict__ outT,
    float* __restrict__ pf)
{
    __shared__ unsigned short tile[32][33];
    __shared__ int dts[6];
    const int blk = blockIdx.x;
    const int t   = threadIdx.x;

    if (blk < 324) {
        if (t == 0) {
            dts[0] = detect_dtype(cw); dts[1] = detect_dtype(cb);
            dts[2] = detect_dtype(db); dts[3] = detect_dtype(Al);
            dts[4] = detect_dtype(Dv); dts[5] = detect_dtype(xp);
        }
        __syncthreads();
        int g = blk * 256 + t;
        if (g >= 82944) return;
        const void* src; int local; int which;
        if      (g <  4608) { src = cw; local = g;         which = 0; }
        else if (g <  6144) { src = cb; local = g - 4608;  which = 1; }
        else if (g <  7680) { src = db; local = g - 6144;  which = 2; }
        else if (g < 32256) { src = Al; local = g - 7680;  which = 3; }
        else if (g < 33792) { src = Dv; local = g - 32256; which = 4; }
        else                { src = xp; local = g - 33792; which = 5; }
        pf[g] = LD(src, local, dts[which]);
    } else if (blk < 3396) {
        if (t == 0) dts[0] = detect_dtype(x);
        __syncthreads();
        const int dt = dts[0];
        size_t i = ((size_t)(blk - 324) * 256 + t) * 4;
        ushort4 o;
        o.x = f2bf(LD(x, i + 0, dt)); o.y = f2bf(LD(x, i + 1, dt));
        o.z = f2bf(LD(x, i + 2, dt)); o.w = f2bf(LD(x, i + 3, dt));
        *(ushort4*)&xb[i] = o;
    } else {
        const void* src; unsigned short* dst; int R, C, tx_n, idx;
        if (blk < 5700)      { src = in_w;  dst = inT;  R = 768;  C = 3072; tx_n = 96; idx = blk - 3396; }
        else if (blk < 8004) { src = dt_w;  dst = dtT;  R = 1536; C = 1536; tx_n = 48; idx = blk - 5700; }
        else                 { src = out_w; dst = outT; R = 1536; C = 768;  tx_n = 24; idx = blk - 8004; }
        if (t == 0) dts[0] = detect_dtype(src);
        __syncthreads();
        const int dt = dts[0];
        const int tx = t & 31, ty = t >> 5;
        const int bx = (idx % tx_n) * 32, by = (idx / tx_n) * 32;
        #pragma unroll
        for (int i = 0; i < 4; ++i) {
            int r = by + ty + i * 8;
            tile[ty + i * 8][tx] = f2bf(LD(src, (size_t)r * C + bx + tx, dt));
        }
        __syncthreads();
        #pragma unroll
        for (int i = 0; i < 4; ++i) {
            int c = bx + ty + i * 8;
            dst[(size_t)c * R + by + tx] = tile[tx][ty + i * 8];
        }
    }
}

// ---- MFMA GEMM: C = A[M][K] @ Bt[N][K]^T, 128x64 tile, double-buffered async ----
// (R14 structure, verbatim.) LDS granule rotation: slot (row, g) holds
// k-granule (g - (row>>1)) & 3.
// EPI 1: bf16 C0 = softplus(v + biasf[col])
// EPI 2: f32  C0 = v (final output)
// EPI 3: col < N/2 -> bf16 C0 = v ; else bf16 C1 = silu(v)
template<int EPI>
__global__ __launch_bounds__(256) void gemm_kernel(
    const unsigned short* __restrict__ A, const unsigned short* __restrict__ Bt,
    void* __restrict__ C0, void* __restrict__ C1, const float* __restrict__ biasf,
    int M, int N, int K)
{
    __shared__ __align__(16) unsigned short As[2][128 * 32];   // 16 KB
    __shared__ __align__(16) unsigned short Bs[2][64 * 32];    // 8 KB
    const int t    = threadIdx.x;
    const int m0   = blockIdx.x * 128;
    const int n0   = blockIdx.y * 64;
    const int w    = t >> 6;
    const int lane = t & 63;
    const int wm   = (w >> 1) * 64, wn = (w & 1) * 32;
    const int lm   = lane & 15, quad = lane >> 4;
    const int srow = lane >> 2;          // staging: row within 16-row group
    const int sg   = lane & 3;           // staging: granule slot

    f32x4 acc[4][2] = {};

    // prologue: stage k0=0 into buffer 0
    #pragma unroll
    for (int h = 0; h < 2; ++h) {
        int row = w * 32 + h * 16 + srow;
        int kg  = (sg - (row >> 1)) & 3;
        async_cp16((glob_us*)&A[(size_t)(m0 + row) * K + kg * 8],
                   (lds_us*)&As[0][(w * 32 + h * 16) * 32]);
    }
    {
        int brow = w * 16 + srow;
        int bkg  = (sg - (brow >> 1)) & 3;
        async_cp16((glob_us*)&Bt[(size_t)(n0 + brow) * K + bkg * 8],
                   (lds_us*)&Bs[0][(w * 16) * 32]);
    }

    int p = 0;
    for (int k0 = 0; k0 < K; k0 += 32) {
        __syncthreads();                       // drains stage(k0); reads of buf p^1 long done
        if (k0 + 32 < K) {                     // stage k0+32 into the other buffer (overlaps MFMA)
            #pragma unroll
            for (int h = 0; h < 2; ++h) {
                int row = w * 32 + h * 16 + srow;
                int kg  = (sg - (row >> 1)) & 3;
                async_cp16((glob_us*)&A[(size_t)(m0 + row) * K + k0 + 32 + kg * 8],
                           (lds_us*)&As[p ^ 1][(w * 32 + h * 16) * 32]);
            }
            int brow = w * 16 + srow;
            int bkg  = (sg - (brow >> 1)) & 3;
            async_cp16((glob_us*)&Bt[(size_t)(n0 + brow) * K + k0 + 32 + bkg * 8],
                       (lds_us*)&Bs[p ^ 1][(w * 16) * 32]);
        }
        bf16x8 af[4], bfr[2];
        #pragma unroll
        for (int i = 0; i < 4; ++i) {
            int row = wm + i * 16 + lm;
            int g   = (quad + (row >> 1)) & 3;
            af[i] = *(const bf16x8*)&As[p][row * 32 + g * 8];
        }
        #pragma unroll
        for (int j = 0; j < 2; ++j) {
            int row = wn + j * 16 + lm;
            int g   = (quad + (row >> 1)) & 3;
            bfr[j] = *(const bf16x8*)&Bs[p][row * 32 + g * 8];
        }
        #pragma unroll
        for (int i = 0; i < 4; ++i)
            #pragma unroll
            for (int j = 0; j < 2; ++j)
                acc[i][j] = __builtin_amdgcn_mfma_f32_16x16x32_bf16(af[i], bfr[j], acc[i][j], 0, 0, 0);
        p ^= 1;
    }

    const int half = N >> 1;
    #pragma unroll
    for (int i = 0; i < 4; ++i) {
        #pragma unroll
        for (int j = 0; j < 2; ++j) {
            int col = n0 + wn + j * 16 + lm;
            #pragma unroll
            for (int r = 0; r < 4; ++r) {
                int row = m0 + wm + i * 16 + quad * 4 + r;
                float v = acc[i][j][r];
                if (EPI == 1) {
                    v += biasf[col];
                    float sp = (v > 20.f) ? v : log1pf(__expf(v));
                    ((unsigned short*)C0)[(size_t)row * N + col] = f2bf(sp);
                } else if (EPI == 2) {
                    ((float*)C0)[(size_t)row * N + col] = v;
                } else {
                    if (col < half) {
                        ((unsigned short*)C0)[(size_t)row * half + col] = f2bf(v);
                    } else {
                        float s = v / (1.f + __expf(-v));
                        ((unsigned short*)C1)[(size_t)row * half + col - half] = f2bf(s);
                    }
                }
            }
        }
    }
}

// ---- depthwise conv3 + bias + SiLU ----
__global__ __launch_bounds__(256) void conv_silu_kernel(
    const unsigned short* __restrict__ xcpre, const float* __restrict__ cwf,
    const float* __restrict__ cbf, unsigned short* __restrict__ xcb)
{
    int idx = blockIdx.x * 256 + threadIdx.x;
    int d   = idx % DINNER;
    int row = idx / DINNER;
    int l   = row % SEQL;
    size_t base = (size_t)row * DINNER + d;
    float acc = cbf[d];
    if (l > 0)        acc += bf2f(xcpre[base - DINNER]) * cwf[d * 3 + 0];
    acc += bf2f(xcpre[base]) * cwf[d * 3 + 1];
    if (l < SEQL - 1) acc += bf2f(xcpre[base + DINNER]) * cwf[d * 3 + 2];
    float s = acc / (1.f + __expf(-acc));
    xcb[base] = f2bf(s);
}

// ---- x_proj: BC[row][32] = xc[row][:] @ xproj_f[1536][32] ----
__global__ __launch_bounds__(128) void xproj_kernel(
    const unsigned short* __restrict__ xcb, const float* __restrict__ wf,
    float* __restrict__ BC)
{
    __shared__ float red[4][32][4];
    const int t = threadIdx.x;
    const int s = t & 31, part = t >> 5;
    const int row0 = blockIdx.x * 4;
    float acc[4] = {0.f, 0.f, 0.f, 0.f};
    for (int k = part * 384; k < (part + 1) * 384; ++k) {
        float wv = wf[k * 32 + s];
        #pragma unroll
        for (int r = 0; r < 4; ++r)
            acc[r] += bf2f(xcb[(size_t)(row0 + r) * DINNER + k]) * wv;
    }
    #pragma unroll
    for (int r = 0; r < 4; ++r) red[part][s][r] = acc[r];
    __syncthreads();
    if (t < 32) {
        #pragma unroll
        for (int r = 0; r < 4; ++r)
            BC[(size_t)(row0 + r) * 32 + t] =
                red[0][t][r] + red[1][t][r] + red[2][t][r] + red[3][t][r];
    }
}

// ============ register-state chunked scan, q-split + software pipeline ============
// Thread g: q = g&3 owns states [4q,4q+4) of d = (g>>2)%DINNER.
// Ping-pong two 4-step register groups: loads for group g+1 are issued before
// computing group g -> counted vmcnt, HBM stream latency hidden under compute.
struct GrpA { unsigned short dv[4], xv[4]; f32x4 Bv[4]; };
struct GrpC { unsigned short dv[4], xv[4], zv[4]; f32x4 Bv[4], Cv[4]; };

__device__ __forceinline__ void ldA(GrpA& gp, const unsigned short* pd,
    const unsigned short* px, const float* pbc, int l) {
    #pragma unroll
    for (int j = 0; j < 4; ++j) {
        size_t o = (size_t)(l + j) * DINNER;
        gp.dv[j] = pd[o];
        gp.xv[j] = px[o];
        gp.Bv[j] = *(const f32x4*)&pbc[(size_t)(l + j) * 32];
    }
}
__device__ __forceinline__ void ldC(GrpC& gp, const unsigned short* pd,
    const unsigned short* px, const unsigned short* pz, const float* pbc, int l) {
    #pragma unroll
    for (int j = 0; j < 4; ++j) {
        size_t o = (size_t)(l + j) * DINNER;
        gp.dv[j] = pd[o];
        gp.xv[j] = px[o];
        gp.zv[j] = pz[o];
        gp.Bv[j] = *(const f32x4*)&pbc[(size_t)(l + j) * 32];
        gp.Cv[j] = *(const f32x4*)&pbc[(size_t)(l + j) * 32 + 16];
    }
}
__device__ __forceinline__ void stepA(const GrpA& gp, const f32x4 A1,
    f32x4& h, float& sdv) {
    #pragma unroll
    for (int j = 0; j < 4; ++j) {
        float dv = bf2f(gp.dv[j]);
        float xv = bf2f(gp.xv[j]);
        float dx = dv * xv;
        sdv += dv;
        f32x4 e;
        e[0] = __expf(dv * A1[0]); e[1] = __expf(dv * A1[1]);
        e[2] = __expf(dv * A1[2]); e[3] = __expf(dv * A1[3]);
        h = e * h + dx * gp.Bv[j];
    }
}
__device__ __forceinline__ void stepC(const GrpC& gp, const f32x4 A1,
    f32x4& h, float Dd, int q, unsigned short* py, int l) {
    #pragma unroll
    for (int j = 0; j < 4; ++j) {
        float dv = bf2f(gp.dv[j]);
        float xv = bf2f(gp.xv[j]);
        float dx = dv * xv;
        f32x4 e;
        e[0] = __expf(dv * A1[0]); e[1] = __expf(dv * A1[1]);
        e[2] = __expf(dv * A1[2]); e[3] = __expf(dv * A1[3]);
        h = e * h + dx * gp.Bv[j];
        f32x4 yv = h * gp.Cv[j];
        float y = yv[0] + yv[1] + yv[2] + yv[3];
        y += __shfl_xor(y, 1);
        y += __shfl_xor(y, 2);
        if (q == 0) {
            float zv = bf2f(gp.zv[j]);
            py[(size_t)(l + j) * DINNER] = f2bf((y + Dd * xv) * zv);
        }
    }
}

__global__ __launch_bounds__(256) void scan_phase_a(
    const unsigned short* __restrict__ dlt, const unsigned short* __restrict__ xcb,
    const float* __restrict__ BC, const float* __restrict__ A_log_f,
    unsigned short* __restrict__ P, float* __restrict__ S)
{
    int g = blockIdx.x * 256 + threadIdx.x;      // [0, 2*32*1536*4)
    int q = g & 3;
    int d = (g >> 2) % DINNER;
    int c = ((g >> 2) / DINNER) % NCHUNK;
    int b = (g >> 2) / (DINNER * NCHUNK);
    f32x4 al = *(const f32x4*)&A_log_f[d * 16 + q * 4];
    f32x4 A1;
    A1[0] = -__expf(al[0]); A1[1] = -__expf(al[1]);
    A1[2] = -__expf(al[2]); A1[3] = -__expf(al[3]);
    f32x4 h = (f32x4){0.f, 0.f, 0.f, 0.f};
    float sdv = 0.f;
    const int row0 = b * SEQL + c * CHLEN;
    const unsigned short* pd = dlt + (size_t)row0 * DINNER + d;
    const unsigned short* px = xcb + (size_t)row0 * DINNER + d;
    const float* pbc = BC + (size_t)row0 * 32 + q * 4;

    GrpA ga, gb;
    ldA(ga, pd, px, pbc, 0);
    for (int l0 = 0; l0 < CHLEN; l0 += 8) {
        ldA(gb, pd, px, pbc, l0 + 4);
        stepA(ga, A1, h, sdv);
        if (l0 + 8 < CHLEN) ldA(ga, pd, px, pbc, l0 + 8);
        stepA(gb, A1, h, sdv);
    }

    size_t idx = (((size_t)(b * NCHUNK + c)) * DINNER + d) * 16 + q * 4;
    *(f32x4*)&S[idx] = h;
    ushort4 pq;
    pq.x = f2bf(__expf(sdv * A1[0]));
    pq.y = f2bf(__expf(sdv * A1[1]));
    pq.z = f2bf(__expf(sdv * A1[2]));
    pq.w = f2bf(__expf(sdv * A1[3]));
    *(ushort4*)&P[idx] = pq;
}

__global__ __launch_bounds__(256) void scan_combine(
    const unsigned short* __restrict__ P, float* __restrict__ S)
{
    int t = blockIdx.x * 256 + threadIdx.x;            // < 2*1536*16
    int b = t / (DINNER * NSTATE);
    int dn = t % (DINNER * NSTATE);
    const size_t stride = (size_t)(DINNER * NSTATE);
    size_t idx = (size_t)b * NCHUNK * stride + dn;
    float Pv = bf2f(P[idx]);
    float Sv = S[idx];
    float H = 0.f;
    for (int c = 0; c < NCHUNK; ++c) {
        float Pn = 0.f, Sn = 0.f;
        if (c + 1 < NCHUNK) {                  // prefetch next chunk
            Pn = bf2f(P[idx + stride]);
            Sn = S[idx + stride];
        }
        S[idx] = H;                 // Hin for chunk c
        H = Pv * H + Sv;
        Pv = Pn; Sv = Sn;
        idx += stride;
    }
}

__global__ __launch_bounds__(256) void scan_phase_c(
    const unsigned short* __restrict__ dlt, const unsigned short* __restrict__ xcb,
    const float* __restrict__ BC, const unsigned short* __restrict__ zg,
    const float* __restrict__ A_log_f, const float* __restrict__ D_f,
    const float* __restrict__ Hin, unsigned short* __restrict__ yg)
{
    int g = blockIdx.x * 256 + threadIdx.x;      // [0, 2*32*1536*4)
    int q = g & 3;
    int d = (g >> 2) % DINNER;
    int c = ((g >> 2) / DINNER) % NCHUNK;
    int b = (g >> 2) / (DINNER * NCHUNK);
    f32x4 al = *(const f32x4*)&A_log_f[d * 16 + q * 4];
    f32x4 A1;
    A1[0] = -__expf(al[0]); A1[1] = -__expf(al[1]);
    A1[2] = -__expf(al[2]); A1[3] = -__expf(al[3]);
    size_t hidx = (((size_t)(b * NCHUNK + c)) * DINNER + d) * 16 + q * 4;
    f32x4 h = *(const f32x4*)&Hin[hidx];
    const float Dd = D_f[d];
    const int row0 = b * SEQL + c * CHLEN;
    const unsigned short* pd = dlt + (size_t)row0 * DINNER + d;
    const unsigned short* px = xcb + (size_t)row0 * DINNER + d;
    const unsigned short* pz = zg  + (size_t)row0 * DINNER + d;
    unsigned short* py = yg + (size_t)row0 * DINNER + d;
    const float* pbc = BC + (size_t)row0 * 32 + q * 4;

    GrpC ga, gb;
    ldC(ga, pd, px, pz, pbc, 0);
    for (int l0 = 0; l0 < CHLEN; l0 += 8) {
        ldC(gb, pd, px, pz, pbc, l0 + 4);
        stepC(ga, A1, h, Dd, q, py, l0);
        if (l0 + 8 < CHLEN) ldC(ga, pd, px, pz, pbc, l0 + 8);
        stepC(gb, A1, h, Dd, q, py, l0 + 4);
    }
}

__global__ void guard_kernel(float* out, int code)
{
    if (threadIdx.x == 0 && blockIdx.x == 0 && code) out[0] = (float)code;
}

extern "C" void kernel_launch(void* const* d_in, const int* in_sizes, int n_in,
                              void* d_out, int out_size, void* d_ws, size_t ws_size,
                              hipStream_t stream) {
    static const int EXPECTED[10] = {3145728, 2359296, 4608, 1536, 49152,
                                     2359296, 1536, 24576, 1536, 1179648};
    bool ok = (n_in == 10);
    if (ok) for (int i = 0; i < 10; ++i) ok = ok && (in_sizes[i] == EXPECTED[i]);
    int code = 0;
    if (!ok) code = 2000;
    else if (ws_size < 67895296ULL) code = 3000;
    if (code) { guard_kernel<<<1, 64, 0, stream>>>((float*)d_out, code); return; }

    const void* x       = d_in[0];
    const void* in_w    = d_in[1];
    const void* conv_w  = d_in[2];
    const void* conv_b  = d_in[3];
    const void* xproj_w = d_in[4];
    const void* dt_w    = d_in[5];
    const void* dt_b    = d_in[6];
    const void* A_log   = d_in[7];
    const void* Dvec    = d_in[8];
    const void* out_w   = d_in[9];

    char* ws = (char*)d_ws;
    float* conv_w_f = (float*)(ws + 0);        // 4608
    float* conv_b_f = (float*)(ws + 18432);    // 1536
    float* dt_b_f   = (float*)(ws + 24576);    // 1536
    float* A_log_f  = (float*)(ws + 30720);    // 24576
    float* D_f      = (float*)(ws + 129024);   // 1536
    float* xproj_f  = (float*)(ws + 135168);   // 49152
    unsigned short* xb    = (unsigned short*)(ws + 524288);    // [4096][768]  (dead after gemm1)
    unsigned short* inT   = (unsigned short*)(ws + 6815744);   // [3072][768]  (dead after gemm1)
    unsigned short* yg    = (unsigned short*)(ws + 524288);    // [4096][1536] alias xb+inT
    unsigned short* dtT   = (unsigned short*)(ws + 13107200);  // [1536][1536]
    unsigned short* outT  = (unsigned short*)(ws + 17825792);  // [768][1536]
    unsigned short* xcpre = (unsigned short*)(ws + 20185088);  // [4096][1536] (dead after conv)
    unsigned short* dlt   = xcpre;                             // alias (gemm2 out)
    float*          BC    = (float*)(ws + 32768000);           // [4096][32]
    unsigned short* zg    = (unsigned short*)(ws + 33292288);  // [4096][1536] silu(z)
    unsigned short* xcb   = (unsigned short*)(ws + 45875200);  // [4096][1536]
    float*          scanS = (float*)(ws + 58458112);           // [2][32][1536][16] f32 6.29MB
    unsigned short* scanP = (unsigned short*)(ws + 64749568);  // same shape bf16   3.15MB

    prep_kernel<<<9156, 256, 0, stream>>>(x, in_w, conv_w, conv_b, xproj_w, dt_w,
                                          dt_b, A_log, Dvec, out_w,
                                          xb, inT, dtT, outT, (float*)ws);

    gemm_kernel<3><<<dim3(32, 48), 256, 0, stream>>>(xb, inT, (void*)xcpre, (void*)zg,
                                                     nullptr, 4096, 3072, 768);
    conv_silu_kernel<<<(4096 * DINNER) / 256, 256, 0, stream>>>(xcpre, conv_w_f, conv_b_f, xcb);
    xproj_kernel<<<1024, 128, 0, stream>>>(xcb, xproj_f, BC);
    gemm_kernel<1><<<dim3(32, 24), 256, 0, stream>>>(xcb, dtT, (void*)dlt, nullptr,
                                                     dt_b_f, 4096, 1536, 1536);
    scan_phase_a<<<1536, 256, 0, stream>>>(dlt, xcb, BC, A_log_f, scanP, scanS);
    scan_combine<<<192, 256, 0, stream>>>(scanP, scanS);
    scan_phase_c<<<1536, 256, 0, stream>>>(dlt, xcb, BC, zg, A_log_f, D_f, scanS, yg);
    gemm_kernel<2><<<dim3(32, 12), 256, 0, stream>>>(yg, outT, d_out, nullptr,
                                                    nullptr, 4096, 768, 1536);
}

// Round 6
// 337.259 us; speedup vs baseline: 1.1467x; 1.0246x over previous
//
#include <hip/hip_runtime.h>
#include <cmath>

// SimplifiedSSM: B=2, L=2048, d_model=768, d_state=16, d_inner=1536
// ROUND 20: GEMM BK 32 -> 64. Per-barrier fixed overhead (~1400+ cy of
// convergence + staged-load drain) dominates the K-loop (R16: counted-vmcnt
// neutral; R17: wave topology neutral). Halve barrier count: each 64-K tile
// = two independent 32-K panels (R14 fragment layout + granule rotation kept
// verbatim), computed back-to-back per phase. LDS 24->48KB (3 blocks/CU ok).
// Scan stays R19 (software-pipelined; phases dropped out of top-5).
#define DMODEL 768
#define DINNER 1536
#define NSTATE 16
#define SEQL   2048
#define NCHUNK 32
#define CHLEN  64      // SEQL / NCHUNK

#define DT_F32  0
#define DT_BF16 1
#define DT_ZERO 2

typedef __bf16 bf16x8 __attribute__((ext_vector_type(8)));
typedef float  f32x4  __attribute__((ext_vector_type(4)));

typedef __attribute__((address_space(3))) unsigned short lds_us;
typedef const __attribute__((address_space(1))) unsigned short glob_us;

__device__ __forceinline__ void async_cp16(glob_us* g, lds_us* l) {
    __builtin_amdgcn_global_load_lds((const __attribute__((address_space(1))) void*)g,
                                     (__attribute__((address_space(3))) void*)l, 16, 0, 0);
}

__device__ __forceinline__ float bf2f(unsigned short h) {
    union { unsigned u; float f; } v; v.u = ((unsigned)h) << 16; return v.f;
}
__device__ __forceinline__ unsigned short f2bf(float f) {
    union { float f; unsigned u; } v; v.f = f;
    unsigned r = (v.u + 0x7FFFu + ((v.u >> 16) & 1u)) >> 16;
    return (unsigned short)r;
}
__device__ int detect_dtype(const void* p) {
    const unsigned* u = (const unsigned*)p;
    int nzlo = 0, band = 0, anynz = 0;
    for (int i = 0; i < 64; ++i) {
        unsigned w = u[i];
        anynz |= (w != 0);
        unsigned lo = w & 0xFFFFu;
        if (lo) {
            ++nzlo;
            unsigned e8 = (lo >> 7) & 0xFF;
            if (e8 >= 0x60 && e8 <= 0x8E) ++band;
        }
    }
    if (nzlo >= 8) return (band * 2 > nzlo) ? DT_BF16 : DT_F32;
    return anynz ? DT_F32 : DT_ZERO;
}
__device__ __forceinline__ float LD(const void* p, size_t i, int dt) {
    if (dt == DT_BF16) return bf2f(((const unsigned short*)p)[i]);
    if (dt == DT_F32)  return ((const float*)p)[i];
    return 0.f;
}

// ---- fused prep: params->f32 | x->bf16 | 3 weight transposes ----
// blocks: [0,324) params, [324,3396) x, [3396,5700) in_w,
//         [5700,8004) dt_w, [8004,9156) out_w
__global__ __launch_bounds__(256) void prep_kernel(
    const void* __restrict__ x, const void* __restrict__ in_w,
    const void* __restrict__ cw, const void* __restrict__ cb,
    const void* __restrict__ xp, const void* __restrict__ dt_w,
    const void* __restrict__ db, const void* __restrict__ Al,
    const void* __restrict__ Dv, const void* __restrict__ out_w,
    unsigned short* __restrict__ xb, unsigned short* __restrict__ inT,
    unsigned short* __restrict__ dtT, unsigned short* __restrict__ outT,
    float* __restrict__ pf)
{
    __shared__ unsigned short tile[32][33];
    __shared__ int dts[6];
    const int blk = blockIdx.x;
    const int t   = threadIdx.x;

    if (blk < 324) {
        if (t == 0) {
            dts[0] = detect_dtype(cw); dts[1] = detect_dtype(cb);
            dts[2] = detect_dtype(db); dts[3] = detect_dtype(Al);
            dts[4] = detect_dtype(Dv); dts[5] = detect_dtype(xp);
        }
        __syncthreads();
        int g = blk * 256 + t;
        if (g >= 82944) return;
        const void* src; int local; int which;
        if      (g <  4608) { src = cw; local = g;         which = 0; }
        else if (g <  6144) { src = cb; local = g - 4608;  which = 1; }
        else if (g <  7680) { src = db; local = g - 6144;  which = 2; }
        else if (g < 32256) { src = Al; local = g - 7680;  which = 3; }
        else if (g < 33792) { src = Dv; local = g - 32256; which = 4; }
        else                { src = xp; local = g - 33792; which = 5; }
        pf[g] = LD(src, local, dts[which]);
    } else if (blk < 3396) {
        if (t == 0) dts[0] = detect_dtype(x);
        __syncthreads();
        const int dt = dts[0];
        size_t i = ((size_t)(blk - 324) * 256 + t) * 4;
        ushort4 o;
        o.x = f2bf(LD(x, i + 0, dt)); o.y = f2bf(LD(x, i + 1, dt));
        o.z = f2bf(LD(x, i + 2, dt)); o.w = f2bf(LD(x, i + 3, dt));
        *(ushort4*)&xb[i] = o;
    } else {
        const void* src; unsigned short* dst; int R, C, tx_n, idx;
        if (blk < 5700)      { src = in_w;  dst = inT;  R = 768;  C = 3072; tx_n = 96; idx = blk - 3396; }
        else if (blk < 8004) { src = dt_w;  dst = dtT;  R = 1536; C = 1536; tx_n = 48; idx = blk - 5700; }
        else                 { src = out_w; dst = outT; R = 1536; C = 768;  tx_n = 24; idx = blk - 8004; }
        if (t == 0) dts[0] = detect_dtype(src);
        __syncthreads();
        const int dt = dts[0];
        const int tx = t & 31, ty = t >> 5;
        const int bx = (idx % tx_n) * 32, by = (idx / tx_n) * 32;
        #pragma unroll
        for (int i = 0; i < 4; ++i) {
            int r = by + ty + i * 8;
            tile[ty + i * 8][tx] = f2bf(LD(src, (size_t)r * C + bx + tx, dt));
        }
        __syncthreads();
        #pragma unroll
        for (int i = 0; i < 4; ++i) {
            int c = bx + ty + i * 8;
            dst[(size_t)c * R + by + tx] = tile[tx][ty + i * 8];
        }
    }
}

// ---- MFMA GEMM: C = A[M][K] @ Bt[N][K]^T, 128x64 tile, BK=64, dbuf async ----
// Each 64-K tile = two 32-K panels with the R14 granule rotation:
// slot (row, g) holds k-granule (g - (row>>1)) & 3 within its panel.
// Per thread per tile: 6 async_cp16 (2A+1B per panel). One barrier per 64-K.
// EPI 1: bf16 C0 = softplus(v + biasf[col])
// EPI 2: f32  C0 = v (final output)
// EPI 3: col < N/2 -> bf16 C0 = v ; else bf16 C1 = silu(v)
template<int EPI>
__global__ __launch_bounds__(256) void gemm_kernel(
    const unsigned short* __restrict__ A, const unsigned short* __restrict__ Bt,
    void* __restrict__ C0, void* __restrict__ C1, const float* __restrict__ biasf,
    int M, int N, int K)
{
    __shared__ __align__(16) unsigned short As[2][2][128 * 32];   // 32 KB
    __shared__ __align__(16) unsigned short Bs[2][2][64 * 32];    // 16 KB
    const int t    = threadIdx.x;
    const int m0   = blockIdx.x * 128;
    const int n0   = blockIdx.y * 64;
    const int w    = t >> 6;
    const int lane = t & 63;
    const int wm   = (w >> 1) * 64, wn = (w & 1) * 32;
    const int lm   = lane & 15, quad = lane >> 4;
    const int srow = lane >> 2;          // staging: row within 16-row group
    const int sg   = lane & 3;           // staging: granule slot

    f32x4 acc[4][2] = {};

    auto stage = [&](int k0, int q) {
        #pragma unroll
        for (int ph = 0; ph < 2; ++ph) {
            #pragma unroll
            for (int h = 0; h < 2; ++h) {
                int row = w * 32 + h * 16 + srow;
                int kg  = (sg - (row >> 1)) & 3;
                async_cp16((glob_us*)&A[(size_t)(m0 + row) * K + k0 + ph * 32 + kg * 8],
                           (lds_us*)&As[q][ph][(w * 32 + h * 16) * 32]);
            }
            int brow = w * 16 + srow;
            int bkg  = (sg - (brow >> 1)) & 3;
            async_cp16((glob_us*)&Bt[(size_t)(n0 + brow) * K + k0 + ph * 32 + bkg * 8],
                       (lds_us*)&Bs[q][ph][(w * 16) * 32]);
        }
    };

    // prologue: stage tile 0 into buffer 0
    stage(0, 0);

    int p = 0;
    for (int k0 = 0; k0 < K; k0 += 64) {
        __syncthreads();                       // drains stage(k0) into buf p
        if (k0 + 64 < K) stage(k0 + 64, p ^ 1);  // overlaps with 16 MFMAs below
        #pragma unroll
        for (int ph = 0; ph < 2; ++ph) {
            bf16x8 af[4], bfr[2];
            #pragma unroll
            for (int i = 0; i < 4; ++i) {
                int row = wm + i * 16 + lm;
                int g   = (quad + (row >> 1)) & 3;
                af[i] = *(const bf16x8*)&As[p][ph][row * 32 + g * 8];
            }
            #pragma unroll
            for (int j = 0; j < 2; ++j) {
                int row = wn + j * 16 + lm;
                int g   = (quad + (row >> 1)) & 3;
                bfr[j] = *(const bf16x8*)&Bs[p][ph][row * 32 + g * 8];
            }
            #pragma unroll
            for (int i = 0; i < 4; ++i)
                #pragma unroll
                for (int j = 0; j < 2; ++j)
                    acc[i][j] = __builtin_amdgcn_mfma_f32_16x16x32_bf16(af[i], bfr[j], acc[i][j], 0, 0, 0);
        }
        p ^= 1;
    }

    const int half = N >> 1;
    #pragma unroll
    for (int i = 0; i < 4; ++i) {
        #pragma unroll
        for (int j = 0; j < 2; ++j) {
            int col = n0 + wn + j * 16 + lm;
            #pragma unroll
            for (int r = 0; r < 4; ++r) {
                int row = m0 + wm + i * 16 + quad * 4 + r;
                float v = acc[i][j][r];
                if (EPI == 1) {
                    v += biasf[col];
                    float sp = (v > 20.f) ? v : log1pf(__expf(v));
                    ((unsigned short*)C0)[(size_t)row * N + col] = f2bf(sp);
                } else if (EPI == 2) {
                    ((float*)C0)[(size_t)row * N + col] = v;
                } else {
                    if (col < half) {
                        ((unsigned short*)C0)[(size_t)row * half + col] = f2bf(v);
                    } else {
                        float s = v / (1.f + __expf(-v));
                        ((unsigned short*)C1)[(size_t)row * half + col - half] = f2bf(s);
                    }
                }
            }
        }
    }
}

// ---- depthwise conv3 + bias + SiLU ----
__global__ __launch_bounds__(256) void conv_silu_kernel(
    const unsigned short* __restrict__ xcpre, const float* __restrict__ cwf,
    const float* __restrict__ cbf, unsigned short* __restrict__ xcb)
{
    int idx = blockIdx.x * 256 + threadIdx.x;
    int d   = idx % DINNER;
    int row = idx / DINNER;
    int l   = row % SEQL;
    size_t base = (size_t)row * DINNER + d;
    float acc = cbf[d];
    if (l > 0)        acc += bf2f(xcpre[base - DINNER]) * cwf[d * 3 + 0];
    acc += bf2f(xcpre[base]) * cwf[d * 3 + 1];
    if (l < SEQL - 1) acc += bf2f(xcpre[base + DINNER]) * cwf[d * 3 + 2];
    float s = acc / (1.f + __expf(-acc));
    xcb[base] = f2bf(s);
}

// ---- x_proj: BC[row][32] = xc[row][:] @ xproj_f[1536][32] ----
__global__ __launch_bounds__(128) void xproj_kernel(
    const unsigned short* __restrict__ xcb, const float* __restrict__ wf,
    float* __restrict__ BC)
{
    __shared__ float red[4][32][4];
    const int t = threadIdx.x;
    const int s = t & 31, part = t >> 5;
    const int row0 = blockIdx.x * 4;
    float acc[4] = {0.f, 0.f, 0.f, 0.f};
    for (int k = part * 384; k < (part + 1) * 384; ++k) {
        float wv = wf[k * 32 + s];
        #pragma unroll
        for (int r = 0; r < 4; ++r)
            acc[r] += bf2f(xcb[(size_t)(row0 + r) * DINNER + k]) * wv;
    }
    #pragma unroll
    for (int r = 0; r < 4; ++r) red[part][s][r] = acc[r];
    __syncthreads();
    if (t < 32) {
        #pragma unroll
        for (int r = 0; r < 4; ++r)
            BC[(size_t)(row0 + r) * 32 + t] =
                red[0][t][r] + red[1][t][r] + red[2][t][r] + red[3][t][r];
    }
}

// ============ register-state chunked scan, q-split + software pipeline ============
// Thread g: q = g&3 owns states [4q,4q+4) of d = (g>>2)%DINNER.
// Ping-pong two 4-step register groups: loads for group g+1 are issued before
// computing group g -> counted vmcnt, HBM stream latency hidden under compute.
struct GrpA { unsigned short dv[4], xv[4]; f32x4 Bv[4]; };
struct GrpC { unsigned short dv[4], xv[4], zv[4]; f32x4 Bv[4], Cv[4]; };

__device__ __forceinline__ void ldA(GrpA& gp, const unsigned short* pd,
    const unsigned short* px, const float* pbc, int l) {
    #pragma unroll
    for (int j = 0; j < 4; ++j) {
        size_t o = (size_t)(l + j) * DINNER;
        gp.dv[j] = pd[o];
        gp.xv[j] = px[o];
        gp.Bv[j] = *(const f32x4*)&pbc[(size_t)(l + j) * 32];
    }
}
__device__ __forceinline__ void ldC(GrpC& gp, const unsigned short* pd,
    const unsigned short* px, const unsigned short* pz, const float* pbc, int l) {
    #pragma unroll
    for (int j = 0; j < 4; ++j) {
        size_t o = (size_t)(l + j) * DINNER;
        gp.dv[j] = pd[o];
        gp.xv[j] = px[o];
        gp.zv[j] = pz[o];
        gp.Bv[j] = *(const f32x4*)&pbc[(size_t)(l + j) * 32];
        gp.Cv[j] = *(const f32x4*)&pbc[(size_t)(l + j) * 32 + 16];
    }
}
__device__ __forceinline__ void stepA(const GrpA& gp, const f32x4 A1,
    f32x4& h, float& sdv) {
    #pragma unroll
    for (int j = 0; j < 4; ++j) {
        float dv = bf2f(gp.dv[j]);
        float xv = bf2f(gp.xv[j]);
        float dx = dv * xv;
        sdv += dv;
        f32x4 e;
        e[0] = __expf(dv * A1[0]); e[1] = __expf(dv * A1[1]);
        e[2] = __expf(dv * A1[2]); e[3] = __expf(dv * A1[3]);
        h = e * h + dx * gp.Bv[j];
    }
}
__device__ __forceinline__ void stepC(const GrpC& gp, const f32x4 A1,
    f32x4& h, float Dd, int q, unsigned short* py, int l) {
    #pragma unroll
    for (int j = 0; j < 4; ++j) {
        float dv = bf2f(gp.dv[j]);
        float xv = bf2f(gp.xv[j]);
        float dx = dv * xv;
        f32x4 e;
        e[0] = __expf(dv * A1[0]); e[1] = __expf(dv * A1[1]);
        e[2] = __expf(dv * A1[2]); e[3] = __expf(dv * A1[3]);
        h = e * h + dx * gp.Bv[j];
        f32x4 yv = h * gp.Cv[j];
        float y = yv[0] + yv[1] + yv[2] + yv[3];
        y += __shfl_xor(y, 1);
        y += __shfl_xor(y, 2);
        if (q == 0) {
            float zv = bf2f(gp.zv[j]);
            py[(size_t)(l + j) * DINNER] = f2bf((y + Dd * xv) * zv);
        }
    }
}

__global__ __launch_bounds__(256) void scan_phase_a(
    const unsigned short* __restrict__ dlt, const unsigned short* __restrict__ xcb,
    const float* __restrict__ BC, const float* __restrict__ A_log_f,
    unsigned short* __restrict__ P, float* __restrict__ S)
{
    int g = blockIdx.x * 256 + threadIdx.x;      // [0, 2*32*1536*4)
    int q = g & 3;
    int d = (g >> 2) % DINNER;
    int c = ((g >> 2) / DINNER) % NCHUNK;
    int b = (g >> 2) / (DINNER * NCHUNK);
    f32x4 al = *(const f32x4*)&A_log_f[d * 16 + q * 4];
    f32x4 A1;
    A1[0] = -__expf(al[0]); A1[1] = -__expf(al[1]);
    A1[2] = -__expf(al[2]); A1[3] = -__expf(al[3]);
    f32x4 h = (f32x4){0.f, 0.f, 0.f, 0.f};
    float sdv = 0.f;
    const int row0 = b * SEQL + c * CHLEN;
    const unsigned short* pd = dlt + (size_t)row0 * DINNER + d;
    const unsigned short* px = xcb + (size_t)row0 * DINNER + d;
    const float* pbc = BC + (size_t)row0 * 32 + q * 4;

    GrpA ga, gb;
    ldA(ga, pd, px, pbc, 0);
    for (int l0 = 0; l0 < CHLEN; l0 += 8) {
        ldA(gb, pd, px, pbc, l0 + 4);
        stepA(ga, A1, h, sdv);
        if (l0 + 8 < CHLEN) ldA(ga, pd, px, pbc, l0 + 8);
        stepA(gb, A1, h, sdv);
    }

    size_t idx = (((size_t)(b * NCHUNK + c)) * DINNER + d) * 16 + q * 4;
    *(f32x4*)&S[idx] = h;
    ushort4 pq;
    pq.x = f2bf(__expf(sdv * A1[0]));
    pq.y = f2bf(__expf(sdv * A1[1]));
    pq.z = f2bf(__expf(sdv * A1[2]));
    pq.w = f2bf(__expf(sdv * A1[3]));
    *(ushort4*)&P[idx] = pq;
}

__global__ __launch_bounds__(256) void scan_combine(
    const unsigned short* __restrict__ P, float* __restrict__ S)
{
    int t = blockIdx.x * 256 + threadIdx.x;            // < 2*1536*16
    int b = t / (DINNER * NSTATE);
    int dn = t % (DINNER * NSTATE);
    const size_t stride = (size_t)(DINNER * NSTATE);
    size_t idx = (size_t)b * NCHUNK * stride + dn;
    float Pv = bf2f(P[idx]);
    float Sv = S[idx];
    float H = 0.f;
    for (int c = 0; c < NCHUNK; ++c) {
        float Pn = 0.f, Sn = 0.f;
        if (c + 1 < NCHUNK) {                  // prefetch next chunk
            Pn = bf2f(P[idx + stride]);
            Sn = S[idx + stride];
        }
        S[idx] = H;                 // Hin for chunk c
        H = Pv * H + Sv;
        Pv = Pn; Sv = Sn;
        idx += stride;
    }
}

__global__ __launch_bounds__(256) void scan_phase_c(
    const unsigned short* __restrict__ dlt, const unsigned short* __restrict__ xcb,
    const float* __restrict__ BC, const unsigned short* __restrict__ zg,
    const float* __restrict__ A_log_f, const float* __restrict__ D_f,
    const float* __restrict__ Hin, unsigned short* __restrict__ yg)
{
    int g = blockIdx.x * 256 + threadIdx.x;      // [0, 2*32*1536*4)
    int q = g & 3;
    int d = (g >> 2) % DINNER;
    int c = ((g >> 2) / DINNER) % NCHUNK;
    int b = (g >> 2) / (DINNER * NCHUNK);
    f32x4 al = *(const f32x4*)&A_log_f[d * 16 + q * 4];
    f32x4 A1;
    A1[0] = -__expf(al[0]); A1[1] = -__expf(al[1]);
    A1[2] = -__expf(al[2]); A1[3] = -__expf(al[3]);
    size_t hidx = (((size_t)(b * NCHUNK + c)) * DINNER + d) * 16 + q * 4;
    f32x4 h = *(const f32x4*)&Hin[hidx];
    const float Dd = D_f[d];
    const int row0 = b * SEQL + c * CHLEN;
    const unsigned short* pd = dlt + (size_t)row0 * DINNER + d;
    const unsigned short* px = xcb + (size_t)row0 * DINNER + d;
    const unsigned short* pz = zg  + (size_t)row0 * DINNER + d;
    unsigned short* py = yg + (size_t)row0 * DINNER + d;
    const float* pbc = BC + (size_t)row0 * 32 + q * 4;

    GrpC ga, gb;
    ldC(ga, pd, px, pz, pbc, 0);
    for (int l0 = 0; l0 < CHLEN; l0 += 8) {
        ldC(gb, pd, px, pz, pbc, l0 + 4);
        stepC(ga, A1, h, Dd, q, py, l0);
        if (l0 + 8 < CHLEN) ldC(ga, pd, px, pz, pbc, l0 + 8);
        stepC(gb, A1, h, Dd, q, py, l0 + 4);
    }
}

__global__ void guard_kernel(float* out, int code)
{
    if (threadIdx.x == 0 && blockIdx.x == 0 && code) out[0] = (float)code;
}

extern "C" void kernel_launch(void* const* d_in, const int* in_sizes, int n_in,
                              void* d_out, int out_size, void* d_ws, size_t ws_size,
                              hipStream_t stream) {
    static const int EXPECTED[10] = {3145728, 2359296, 4608, 1536, 49152,
                                     2359296, 1536, 24576, 1536, 1179648};
    bool ok = (n_in == 10);
    if (ok) for (int i = 0; i < 10; ++i) ok = ok && (in_sizes[i] == EXPECTED[i]);
    int code = 0;
    if (!ok) code = 2000;
    else if (ws_size < 67895296ULL) code = 3000;
    if (code) { guard_kernel<<<1, 64, 0, stream>>>((float*)d_out, code); return; }

    const void* x       = d_in[0];
    const void* in_w    = d_in[1];
    const void* conv_w  = d_in[2];
    const void* conv_b  = d_in[3];
    const void* xproj_w = d_in[4];
    const void* dt_w    = d_in[5];
    const void* dt_b    = d_in[6];
    const void* A_log   = d_in[7];
    const void* Dvec    = d_in[8];
    const void* out_w   = d_in[9];

    char* ws = (char*)d_ws;
    float* conv_w_f = (float*)(ws + 0);        // 4608
    float* conv_b_f = (float*)(ws + 18432);    // 1536
    float* dt_b_f   = (float*)(ws + 24576);    // 1536
    float* A_log_f  = (float*)(ws + 30720);    // 24576
    float* D_f      = (float*)(ws + 129024);   // 1536
    float* xproj_f  = (float*)(ws + 135168);   // 49152
    unsigned short* xb    = (unsigned short*)(ws + 524288);    // [4096][768]  (dead after gemm1)
    unsigned short* inT   = (unsigned short*)(ws + 6815744);   // [3072][768]  (dead after gemm1)
    unsigned short* yg    = (unsigned short*)(ws + 524288);    // [4096][1536] alias xb+inT
    unsigned short* dtT   = (unsigned short*)(ws + 13107200);  // [1536][1536]
    unsigned short* outT  = (unsigned short*)(ws + 17825792);  // [768][1536]
    unsigned short* xcpre = (unsigned short*)(ws + 20185088);  // [4096][1536] (dead after conv)
    unsigned short* dlt   = xcpre;                             // alias (gemm2 out)
    float*          BC    = (float*)(ws + 32768000);           // [4096][32]
    unsigned short* zg    = (unsigned short*)(ws + 33292288);  // [4096][1536] silu(z)
    unsigned short* xcb   = (unsigned short*)(ws + 45875200);  // [4096][1536]
    float*          scanS = (float*)(ws + 58458112);           // [2][32][1536][16] f32 6.29MB
    unsigned short* scanP = (unsigned short*)(ws + 64749568);  // same shape bf16   3.15MB

    prep_kernel<<<9156, 256, 0, stream>>>(x, in_w, conv_w, conv_b, xproj_w, dt_w,
                                          dt_b, A_log, Dvec, out_w,
                                          xb, inT, dtT, outT, (float*)ws);

    gemm_kernel<3><<<dim3(32, 48), 256, 0, stream>>>(xb, inT, (void*)xcpre, (void*)zg,
                                                     nullptr, 4096, 3072, 768);
    conv_silu_kernel<<<(4096 * DINNER) / 256, 256, 0, stream>>>(xcpre, conv_w_f, conv_b_f, xcb);
    xproj_kernel<<<1024, 128, 0, stream>>>(xcb, xproj_f, BC);
    gemm_kernel<1><<<dim3(32, 24), 256, 0, stream>>>(xcb, dtT, (void*)dlt, nullptr,
                                                     dt_b_f, 4096, 1536, 1536);
    scan_phase_a<<<1536, 256, 0, stream>>>(dlt, xcb, BC, A_log_f, scanP, scanS);
    scan_combine<<<192, 256, 0, stream>>>(scanP, scanS);
    scan_phase_c<<<1536, 256, 0, stream>>>(dlt, xcb, BC, zg, A_log_f, D_f, scanS, yg);
    gemm_kernel<2><<<dim3(32, 12), 256, 0, stream>>>(yg, outT, d_out, nullptr,
                                                    nullptr, 4096, 768, 1536);
}

// Round 7
// 322.497 us; speedup vs baseline: 1.1992x; 1.0458x over previous
//
#include <hip/hip_runtime.h>
#include <cmath>

// SimplifiedSSM: B=2, L=2048, d_model=768, d_state=16, d_inner=1536
// ROUND 21: GEMMs frozen (R20 BK=64; at the 2-phase structure's shape-curve
// ceiling ~350 TF for these N/K). NEW: (1) prep rewritten -- 64x64 transpose
// tiles, float4 reads, ushort4 writes, 16 elem/thread (was 4, scalar); x-cast
// 8/thread; grid 9156->3300. (2) scans use exp2 with prep-folded A2 =
// -exp(A_log)*log2e (saves 1 VALU mul per state-step + init exps). (3)
// phase_c rotated stores: lane q stores step l0+q unconditionally, z loaded
// once per group per lane (no exec-mask churn).
#define DMODEL 768
#define DINNER 1536
#define NSTATE 16
#define SEQL   2048
#define NCHUNK 32
#define CHLEN  64      // SEQL / NCHUNK

#define DT_F32  0
#define DT_BF16 1
#define DT_ZERO 2

typedef __bf16 bf16x8 __attribute__((ext_vector_type(8)));
typedef float  f32x4  __attribute__((ext_vector_type(4)));

typedef __attribute__((address_space(3))) unsigned short lds_us;
typedef const __attribute__((address_space(1))) unsigned short glob_us;

__device__ __forceinline__ void async_cp16(glob_us* g, lds_us* l) {
    __builtin_amdgcn_global_load_lds((const __attribute__((address_space(1))) void*)g,
                                     (__attribute__((address_space(3))) void*)l, 16, 0, 0);
}

__device__ __forceinline__ float bf2f(unsigned short h) {
    union { unsigned u; float f; } v; v.u = ((unsigned)h) << 16; return v.f;
}
__device__ __forceinline__ unsigned short f2bf(float f) {
    union { float f; unsigned u; } v; v.f = f;
    unsigned r = (v.u + 0x7FFFu + ((v.u >> 16) & 1u)) >> 16;
    return (unsigned short)r;
}
__device__ int detect_dtype(const void* p) {
    const unsigned* u = (const unsigned*)p;
    int nzlo = 0, band = 0, anynz = 0;
    for (int i = 0; i < 64; ++i) {
        unsigned w = u[i];
        anynz |= (w != 0);
        unsigned lo = w & 0xFFFFu;
        if (lo) {
            ++nzlo;
            unsigned e8 = (lo >> 7) & 0xFF;
            if (e8 >= 0x60 && e8 <= 0x8E) ++band;
        }
    }
    if (nzlo >= 8) return (band * 2 > nzlo) ? DT_BF16 : DT_F32;
    return anynz ? DT_F32 : DT_ZERO;
}
__device__ __forceinline__ float LD(const void* p, size_t i, int dt) {
    if (dt == DT_BF16) return bf2f(((const unsigned short*)p)[i]);
    if (dt == DT_F32)  return ((const float*)p)[i];
    return 0.f;
}

// ---- fused prep: params->f32 (A_log -> A2) | x->bf16 | 3 weight transposes ----
// blocks: [0,324) params, [324,1860) x (8 elem/thread),
//         [1860,2436) in_w, [2436,3012) dt_w, [3012,3300) out_w (64x64 tiles)
__global__ __launch_bounds__(256) void prep_kernel(
    const void* __restrict__ x, const void* __restrict__ in_w,
    const void* __restrict__ cw, const void* __restrict__ cb,
    const void* __restrict__ xp, const void* __restrict__ dt_w,
    const void* __restrict__ db, const void* __restrict__ Al,
    const void* __restrict__ Dv, const void* __restrict__ out_w,
    unsigned short* __restrict__ xb, unsigned short* __restrict__ inT,
    unsigned short* __restrict__ dtT, unsigned short* __restrict__ outT,
    float* __restrict__ pf)
{
    __shared__ unsigned short tile[64][68];
    __shared__ int dts[6];
    const int blk = blockIdx.x;
    const int t   = threadIdx.x;

    if (blk < 324) {
        if (t == 0) {
            dts[0] = detect_dtype(cw); dts[1] = detect_dtype(cb);
            dts[2] = detect_dtype(db); dts[3] = detect_dtype(Al);
            dts[4] = detect_dtype(Dv); dts[5] = detect_dtype(xp);
        }
        __syncthreads();
        int g = blk * 256 + t;
        if (g >= 82944) return;
        const void* src; int local; int which;
        if      (g <  4608) { src = cw; local = g;         which = 0; }
        else if (g <  6144) { src = cb; local = g - 4608;  which = 1; }
        else if (g <  7680) { src = db; local = g - 6144;  which = 2; }
        else if (g < 32256) { src = Al; local = g - 7680;  which = 3; }
        else if (g < 33792) { src = Dv; local = g - 32256; which = 4; }
        else                { src = xp; local = g - 33792; which = 5; }
        float v = LD(src, local, dts[which]);
        if (which == 3) v = -__expf(v) * 1.44269504f;   // A2 = -exp(A_log)*log2e
        pf[g] = v;
    } else if (blk < 1860) {
        if (t == 0) dts[0] = detect_dtype(x);
        __syncthreads();
        const int dt = dts[0];
        size_t i = ((size_t)(blk - 324) * 256 + t) * 8;
        ushort4 o0, o1;
        if (dt == DT_F32) {
            float4 a = *(const float4*)((const float*)x + i);
            float4 b = *(const float4*)((const float*)x + i + 4);
            o0.x = f2bf(a.x); o0.y = f2bf(a.y); o0.z = f2bf(a.z); o0.w = f2bf(a.w);
            o1.x = f2bf(b.x); o1.y = f2bf(b.y); o1.z = f2bf(b.z); o1.w = f2bf(b.w);
        } else if (dt == DT_BF16) {
            o0 = *(const ushort4*)((const unsigned short*)x + i);
            o1 = *(const ushort4*)((const unsigned short*)x + i + 4);
        } else {
            o0 = (ushort4){0,0,0,0}; o1 = (ushort4){0,0,0,0};
        }
        *(ushort4*)&xb[i] = o0;
        *(ushort4*)&xb[i + 4] = o1;
    } else {
        const void* src; unsigned short* dst; int R, C, tx_n, idx;
        if (blk < 2436)      { src = in_w;  dst = inT;  R = 768;  C = 3072; tx_n = 48; idx = blk - 1860; }
        else if (blk < 3012) { src = dt_w;  dst = dtT;  R = 1536; C = 1536; tx_n = 24; idx = blk - 2436; }
        else                 { src = out_w; dst = outT; R = 1536; C = 768;  tx_n = 12; idx = blk - 3012; }
        if (t == 0) dts[0] = detect_dtype(src);
        __syncthreads();
        const int dt = dts[0];
        const int tx = t & 15, ty = t >> 4;          // 16 x 16 threads
        const int bx = (idx % tx_n) * 64, by = (idx / tx_n) * 64;
        #pragma unroll
        for (int i = 0; i < 4; ++i) {
            int rl = ty + i * 16;
            size_t soff = (size_t)(by + rl) * C + bx + tx * 4;
            ushort4 hv;
            if (dt == DT_F32) {
                float4 v = *(const float4*)((const float*)src + soff);
                hv.x = f2bf(v.x); hv.y = f2bf(v.y); hv.z = f2bf(v.z); hv.w = f2bf(v.w);
            } else if (dt == DT_BF16) {
                hv = *(const ushort4*)((const unsigned short*)src + soff);
            } else {
                hv = (ushort4){0,0,0,0};
            }
            *(ushort4*)&tile[rl][tx * 4] = hv;
        }
        __syncthreads();
        #pragma unroll
        for (int i = 0; i < 4; ++i) {
            int cl = ty + i * 16;
            int m0 = tx * 4;
            ushort4 o;
            o.x = tile[m0 + 0][cl]; o.y = tile[m0 + 1][cl];
            o.z = tile[m0 + 2][cl]; o.w = tile[m0 + 3][cl];
            *(ushort4*)&dst[(size_t)(bx + cl) * R + by + m0] = o;
        }
    }
}

// ---- MFMA GEMM: C = A[M][K] @ Bt[N][K]^T, 128x64 tile, BK=64, dbuf async ----
// (R20 structure, frozen.) Granule rotation: slot (row,g) holds k-granule
// (g - (row>>1)) & 3 within its 32-K panel.
// EPI 1: bf16 C0 = softplus(v + biasf[col])
// EPI 2: f32  C0 = v (final output)
// EPI 3: col < N/2 -> bf16 C0 = v ; else bf16 C1 = silu(v)
template<int EPI>
__global__ __launch_bounds__(256) void gemm_kernel(
    const unsigned short* __restrict__ A, const unsigned short* __restrict__ Bt,
    void* __restrict__ C0, void* __restrict__ C1, const float* __restrict__ biasf,
    int M, int N, int K)
{
    __shared__ __align__(16) unsigned short As[2][2][128 * 32];   // 32 KB
    __shared__ __align__(16) unsigned short Bs[2][2][64 * 32];    // 16 KB
    const int t    = threadIdx.x;
    const int m0   = blockIdx.x * 128;
    const int n0   = blockIdx.y * 64;
    const int w    = t >> 6;
    const int lane = t & 63;
    const int wm   = (w >> 1) * 64, wn = (w & 1) * 32;
    const int lm   = lane & 15, quad = lane >> 4;
    const int srow = lane >> 2;          // staging: row within 16-row group
    const int sg   = lane & 3;           // staging: granule slot

    f32x4 acc[4][2] = {};

    auto stage = [&](int k0, int q) {
        #pragma unroll
        for (int ph = 0; ph < 2; ++ph) {
            #pragma unroll
            for (int h = 0; h < 2; ++h) {
                int row = w * 32 + h * 16 + srow;
                int kg  = (sg - (row >> 1)) & 3;
                async_cp16((glob_us*)&A[(size_t)(m0 + row) * K + k0 + ph * 32 + kg * 8],
                           (lds_us*)&As[q][ph][(w * 32 + h * 16) * 32]);
            }
            int brow = w * 16 + srow;
            int bkg  = (sg - (brow >> 1)) & 3;
            async_cp16((glob_us*)&Bt[(size_t)(n0 + brow) * K + k0 + ph * 32 + bkg * 8],
                       (lds_us*)&Bs[q][ph][(w * 16) * 32]);
        }
    };

    // prologue: stage tile 0 into buffer 0
    stage(0, 0);

    int p = 0;
    for (int k0 = 0; k0 < K; k0 += 64) {
        __syncthreads();                       // drains stage(k0) into buf p
        if (k0 + 64 < K) stage(k0 + 64, p ^ 1);  // overlaps with 16 MFMAs below
        #pragma unroll
        for (int ph = 0; ph < 2; ++ph) {
            bf16x8 af[4], bfr[2];
            #pragma unroll
            for (int i = 0; i < 4; ++i) {
                int row = wm + i * 16 + lm;
                int g   = (quad + (row >> 1)) & 3;
                af[i] = *(const bf16x8*)&As[p][ph][row * 32 + g * 8];
            }
            #pragma unroll
            for (int j = 0; j < 2; ++j) {
                int row = wn + j * 16 + lm;
                int g   = (quad + (row >> 1)) & 3;
                bfr[j] = *(const bf16x8*)&Bs[p][ph][row * 32 + g * 8];
            }
            #pragma unroll
            for (int i = 0; i < 4; ++i)
                #pragma unroll
                for (int j = 0; j < 2; ++j)
                    acc[i][j] = __builtin_amdgcn_mfma_f32_16x16x32_bf16(af[i], bfr[j], acc[i][j], 0, 0, 0);
        }
        p ^= 1;
    }

    const int half = N >> 1;
    #pragma unroll
    for (int i = 0; i < 4; ++i) {
        #pragma unroll
        for (int j = 0; j < 2; ++j) {
            int col = n0 + wn + j * 16 + lm;
            #pragma unroll
            for (int r = 0; r < 4; ++r) {
                int row = m0 + wm + i * 16 + quad * 4 + r;
                float v = acc[i][j][r];
                if (EPI == 1) {
                    v += biasf[col];
                    float sp = (v > 20.f) ? v : log1pf(__expf(v));
                    ((unsigned short*)C0)[(size_t)row * N + col] = f2bf(sp);
                } else if (EPI == 2) {
                    ((float*)C0)[(size_t)row * N + col] = v;
                } else {
                    if (col < half) {
                        ((unsigned short*)C0)[(size_t)row * half + col] = f2bf(v);
                    } else {
                        float s = v / (1.f + __expf(-v));
                        ((unsigned short*)C1)[(size_t)row * half + col - half] = f2bf(s);
                    }
                }
            }
        }
    }
}

// ---- depthwise conv3 + bias + SiLU ----
__global__ __launch_bounds__(256) void conv_silu_kernel(
    const unsigned short* __restrict__ xcpre, const float* __restrict__ cwf,
    const float* __restrict__ cbf, unsigned short* __restrict__ xcb)
{
    int idx = blockIdx.x * 256 + threadIdx.x;
    int d   = idx % DINNER;
    int row = idx / DINNER;
    int l   = row % SEQL;
    size_t base = (size_t)row * DINNER + d;
    float acc = cbf[d];
    if (l > 0)        acc += bf2f(xcpre[base - DINNER]) * cwf[d * 3 + 0];
    acc += bf2f(xcpre[base]) * cwf[d * 3 + 1];
    if (l < SEQL - 1) acc += bf2f(xcpre[base + DINNER]) * cwf[d * 3 + 2];
    float s = acc / (1.f + __expf(-acc));
    xcb[base] = f2bf(s);
}

// ---- x_proj: BC[row][32] = xc[row][:] @ xproj_f[1536][32] ----
__global__ __launch_bounds__(128) void xproj_kernel(
    const unsigned short* __restrict__ xcb, const float* __restrict__ wf,
    float* __restrict__ BC)
{
    __shared__ float red[4][32][4];
    const int t = threadIdx.x;
    const int s = t & 31, part = t >> 5;
    const int row0 = blockIdx.x * 4;
    float acc[4] = {0.f, 0.f, 0.f, 0.f};
    for (int k = part * 384; k < (part + 1) * 384; ++k) {
        float wv = wf[k * 32 + s];
        #pragma unroll
        for (int r = 0; r < 4; ++r)
            acc[r] += bf2f(xcb[(size_t)(row0 + r) * DINNER + k]) * wv;
    }
    #pragma unroll
    for (int r = 0; r < 4; ++r) red[part][s][r] = acc[r];
    __syncthreads();
    if (t < 32) {
        #pragma unroll
        for (int r = 0; r < 4; ++r)
            BC[(size_t)(row0 + r) * 32 + t] =
                red[0][t][r] + red[1][t][r] + red[2][t][r] + red[3][t][r];
    }
}

// ============ register-state chunked scan, q-split + software pipeline ============
// Thread g: q = g&3 owns states [4q,4q+4) of d = (g>>2)%DINNER.
// A2 = -exp(A_log)*log2e precomputed in prep; decay = exp2(dv*A2).
// Ping-pong two 4-step register groups (loads for g+1 before computing g).
struct GrpA { unsigned short dv[4], xv[4]; f32x4 Bv[4]; };
struct GrpC { unsigned short dv[4], xv[4], zq; f32x4 Bv[4], Cv[4]; };

__device__ __forceinline__ void ldA(GrpA& gp, const unsigned short* pd,
    const unsigned short* px, const float* pbc, int l) {
    #pragma unroll
    for (int j = 0; j < 4; ++j) {
        size_t o = (size_t)(l + j) * DINNER;
        gp.dv[j] = pd[o];
        gp.xv[j] = px[o];
        gp.Bv[j] = *(const f32x4*)&pbc[(size_t)(l + j) * 32];
    }
}
__device__ __forceinline__ void ldC(GrpC& gp, const unsigned short* pd,
    const unsigned short* px, const unsigned short* pz, const float* pbc,
    int l, int q) {
    #pragma unroll
    for (int j = 0; j < 4; ++j) {
        size_t o = (size_t)(l + j) * DINNER;
        gp.dv[j] = pd[o];
        gp.xv[j] = px[o];
        gp.Bv[j] = *(const f32x4*)&pbc[(size_t)(l + j) * 32];
        gp.Cv[j] = *(const f32x4*)&pbc[(size_t)(l + j) * 32 + 16];
    }
    gp.zq = pz[(size_t)(l + q) * DINNER];
}
__device__ __forceinline__ void stepA(const GrpA& gp, const f32x4 A2,
    f32x4& h, float& sdv) {
    #pragma unroll
    for (int j = 0; j < 4; ++j) {
        float dv = bf2f(gp.dv[j]);
        float xv = bf2f(gp.xv[j]);
        float dx = dv * xv;
        sdv += dv;
        f32x4 e;
        e[0] = __builtin_amdgcn_exp2f(dv * A2[0]);
        e[1] = __builtin_amdgcn_exp2f(dv * A2[1]);
        e[2] = __builtin_amdgcn_exp2f(dv * A2[2]);
        e[3] = __builtin_amdgcn_exp2f(dv * A2[3]);
        h = e * h + dx * gp.Bv[j];
    }
}
__device__ __forceinline__ void stepC(const GrpC& gp, const f32x4 A2,
    f32x4& h, float Dd, int q, unsigned short* py, int l) {
    float yq = 0.f, xq = 0.f;
    #pragma unroll
    for (int j = 0; j < 4; ++j) {
        float dv = bf2f(gp.dv[j]);
        float xv = bf2f(gp.xv[j]);
        float dx = dv * xv;
        f32x4 e;
        e[0] = __builtin_amdgcn_exp2f(dv * A2[0]);
        e[1] = __builtin_amdgcn_exp2f(dv * A2[1]);
        e[2] = __builtin_amdgcn_exp2f(dv * A2[2]);
        e[3] = __builtin_amdgcn_exp2f(dv * A2[3]);
        h = e * h + dx * gp.Bv[j];
        f32x4 yv = h * gp.Cv[j];
        float y = yv[0] + yv[1] + yv[2] + yv[3];
        y += __shfl_xor(y, 1);
        y += __shfl_xor(y, 2);
        if (j == q) { yq = y; xq = xv; }   // j is compile-time -> cndmask select
    }
    float zv = bf2f(gp.zq);
    py[(size_t)(l + q) * DINNER] = f2bf((yq + Dd * xq) * zv);
}

__global__ __launch_bounds__(256) void scan_phase_a(
    const unsigned short* __restrict__ dlt, const unsigned short* __restrict__ xcb,
    const float* __restrict__ BC, const float* __restrict__ A_log_f,
    unsigned short* __restrict__ P, float* __restrict__ S)
{
    int g = blockIdx.x * 256 + threadIdx.x;      // [0, 2*32*1536*4)
    int q = g & 3;
    int d = (g >> 2) % DINNER;
    int c = ((g >> 2) / DINNER) % NCHUNK;
    int b = (g >> 2) / (DINNER * NCHUNK);
    f32x4 A2 = *(const f32x4*)&A_log_f[d * 16 + q * 4];
    f32x4 h = (f32x4){0.f, 0.f, 0.f, 0.f};
    float sdv = 0.f;
    const int row0 = b * SEQL + c * CHLEN;
    const unsigned short* pd = dlt + (size_t)row0 * DINNER + d;
    const unsigned short* px = xcb + (size_t)row0 * DINNER + d;
    const float* pbc = BC + (size_t)row0 * 32 + q * 4;

    GrpA ga, gb;
    ldA(ga, pd, px, pbc, 0);
    for (int l0 = 0; l0 < CHLEN; l0 += 8) {
        ldA(gb, pd, px, pbc, l0 + 4);
        stepA(ga, A2, h, sdv);
        if (l0 + 8 < CHLEN) ldA(ga, pd, px, pbc, l0 + 8);
        stepA(gb, A2, h, sdv);
    }

    size_t idx = (((size_t)(b * NCHUNK + c)) * DINNER + d) * 16 + q * 4;
    *(f32x4*)&S[idx] = h;
    ushort4 pq;
    pq.x = f2bf(__builtin_amdgcn_exp2f(sdv * A2[0]));
    pq.y = f2bf(__builtin_amdgcn_exp2f(sdv * A2[1]));
    pq.z = f2bf(__builtin_amdgcn_exp2f(sdv * A2[2]));
    pq.w = f2bf(__builtin_amdgcn_exp2f(sdv * A2[3]));
    *(ushort4*)&P[idx] = pq;
}

__global__ __launch_bounds__(256) void scan_combine(
    const unsigned short* __restrict__ P, float* __restrict__ S)
{
    int t = blockIdx.x * 256 + threadIdx.x;            // < 2*1536*16
    int b = t / (DINNER * NSTATE);
    int dn = t % (DINNER * NSTATE);
    const size_t stride = (size_t)(DINNER * NSTATE);
    size_t idx = (size_t)b * NCHUNK * stride + dn;
    float Pv = bf2f(P[idx]);
    float Sv = S[idx];
    float H = 0.f;
    for (int c = 0; c < NCHUNK; ++c) {
        float Pn = 0.f, Sn = 0.f;
        if (c + 1 < NCHUNK) {                  // prefetch next chunk
            Pn = bf2f(P[idx + stride]);
            Sn = S[idx + stride];
        }
        S[idx] = H;                 // Hin for chunk c
        H = Pv * H + Sv;
        Pv = Pn; Sv = Sn;
        idx += stride;
    }
}

__global__ __launch_bounds__(256) void scan_phase_c(
    const unsigned short* __restrict__ dlt, const unsigned short* __restrict__ xcb,
    const float* __restrict__ BC, const unsigned short* __restrict__ zg,
    const float* __restrict__ A_log_f, const float* __restrict__ D_f,
    const float* __restrict__ Hin, unsigned short* __restrict__ yg)
{
    int g = blockIdx.x * 256 + threadIdx.x;      // [0, 2*32*1536*4)
    int q = g & 3;
    int d = (g >> 2) % DINNER;
    int c = ((g >> 2) / DINNER) % NCHUNK;
    int b = (g >> 2) / (DINNER * NCHUNK);
    f32x4 A2 = *(const f32x4*)&A_log_f[d * 16 + q * 4];
    size_t hidx = (((size_t)(b * NCHUNK + c)) * DINNER + d) * 16 + q * 4;
    f32x4 h = *(const f32x4*)&Hin[hidx];
    const float Dd = D_f[d];
    const int row0 = b * SEQL + c * CHLEN;
    const unsigned short* pd = dlt + (size_t)row0 * DINNER + d;
    const unsigned short* px = xcb + (size_t)row0 * DINNER + d;
    const unsigned short* pz = zg  + (size_t)row0 * DINNER + d;
    unsigned short* py = yg + (size_t)row0 * DINNER + d;
    const float* pbc = BC + (size_t)row0 * 32 + q * 4;

    GrpC ga, gb;
    ldC(ga, pd, px, pz, pbc, 0, q);
    for (int l0 = 0; l0 < CHLEN; l0 += 8) {
        ldC(gb, pd, px, pz, pbc, l0 + 4, q);
        stepC(ga, A2, h, Dd, q, py, l0);
        if (l0 + 8 < CHLEN) ldC(ga, pd, px, pz, pbc, l0 + 8, q);
        stepC(gb, A2, h, Dd, q, py, l0 + 4);
    }
}

__global__ void guard_kernel(float* out, int code)
{
    if (threadIdx.x == 0 && blockIdx.x == 0 && code) out[0] = (float)code;
}

extern "C" void kernel_launch(void* const* d_in, const int* in_sizes, int n_in,
                              void* d_out, int out_size, void* d_ws, size_t ws_size,
                              hipStream_t stream) {
    static const int EXPECTED[10] = {3145728, 2359296, 4608, 1536, 49152,
                                     2359296, 1536, 24576, 1536, 1179648};
    bool ok = (n_in == 10);
    if (ok) for (int i = 0; i < 10; ++i) ok = ok && (in_sizes[i] == EXPECTED[i]);
    int code = 0;
    if (!ok) code = 2000;
    else if (ws_size < 67895296ULL) code = 3000;
    if (code) { guard_kernel<<<1, 64, 0, stream>>>((float*)d_out, code); return; }

    const void* x       = d_in[0];
    const void* in_w    = d_in[1];
    const void* conv_w  = d_in[2];
    const void* conv_b  = d_in[3];
    const void* xproj_w = d_in[4];
    const void* dt_w    = d_in[5];
    const void* dt_b    = d_in[6];
    const void* A_log   = d_in[7];
    const void* Dvec    = d_in[8];
    const void* out_w   = d_in[9];

    char* ws = (char*)d_ws;
    float* conv_w_f = (float*)(ws + 0);        // 4608
    float* conv_b_f = (float*)(ws + 18432);    // 1536
    float* dt_b_f   = (float*)(ws + 24576);    // 1536
    float* A_log_f  = (float*)(ws + 30720);    // 24576 (holds A2 = -exp(A_log)*log2e)
    float* D_f      = (float*)(ws + 129024);   // 1536
    float* xproj_f  = (float*)(ws + 135168);   // 49152
    unsigned short* xb    = (unsigned short*)(ws + 524288);    // [4096][768]  (dead after gemm1)
    unsigned short* inT   = (unsigned short*)(ws + 6815744);   // [3072][768]  (dead after gemm1)
    unsigned short* yg    = (unsigned short*)(ws + 524288);    // [4096][1536] alias xb+inT
    unsigned short* dtT   = (unsigned short*)(ws + 13107200);  // [1536][1536]
    unsigned short* outT  = (unsigned short*)(ws + 17825792);  // [768][1536]
    unsigned short* xcpre = (unsigned short*)(ws + 20185088);  // [4096][1536] (dead after conv)
    unsigned short* dlt   = xcpre;                             // alias (gemm2 out)
    float*          BC    = (float*)(ws + 32768000);           // [4096][32]
    unsigned short* zg    = (unsigned short*)(ws + 33292288);  // [4096][1536] silu(z)
    unsigned short* xcb   = (unsigned short*)(ws + 45875200);  // [4096][1536]
    float*          scanS = (float*)(ws + 58458112);           // [2][32][1536][16] f32 6.29MB
    unsigned short* scanP = (unsigned short*)(ws + 64749568);  // same shape bf16   3.15MB

    prep_kernel<<<3300, 256, 0, stream>>>(x, in_w, conv_w, conv_b, xproj_w, dt_w,
                                          dt_b, A_log, Dvec, out_w,
                                          xb, inT, dtT, outT, (float*)ws);

    gemm_kernel<3><<<dim3(32, 48), 256, 0, stream>>>(xb, inT, (void*)xcpre, (void*)zg,
                                                     nullptr, 4096, 3072, 768);
    conv_silu_kernel<<<(4096 * DINNER) / 256, 256, 0, stream>>>(xcpre, conv_w_f, conv_b_f, xcb);
    xproj_kernel<<<1024, 128, 0, stream>>>(xcb, xproj_f, BC);
    gemm_kernel<1><<<dim3(32, 24), 256, 0, stream>>>(xcb, dtT, (void*)dlt, nullptr,
                                                     dt_b_f, 4096, 1536, 1536);
    scan_phase_a<<<1536, 256, 0, stream>>>(dlt, xcb, BC, A_log_f, scanP, scanS);
    scan_combine<<<192, 256, 0, stream>>>(scanP, scanS);
    scan_phase_c<<<1536, 256, 0, stream>>>(dlt, xcb, BC, zg, A_log_f, D_f, scanS, yg);
    gemm_kernel<2><<<dim3(32, 12), 256, 0, stream>>>(yg, outT, d_out, nullptr,
                                                    nullptr, 4096, 768, 1536);
}